// Round 1
// baseline (384.309 us; speedup 1.0000x reference)
//
#include <hip/hip_runtime.h>

#define NTOT 1536
#define DD 2048
#define BB 4
#define SS 4096
#define NBB 42          // partial blocks per (group,b)
#define TPB 98          // ceil(4096/42)

// ---------------- kernel 0: normalize neuron_emb rows ----------------
__global__ __launch_bounds__(256) void k_norm(const float* __restrict__ emb,
                                              float* __restrict__ out) {
  int wave = threadIdx.x >> 6;
  int lane = threadIdx.x & 63;
  int n = blockIdx.x * 4 + wave;          // grid 384 * 4 = 1536 exactly
  float v = emb[n * 64 + lane];
  float ss = v * v;
#pragma unroll
  for (int off = 32; off; off >>= 1) ss += __shfl_xor(ss, off, 64);
  float nrm = fmaxf(sqrtf(ss), 1e-12f);
  out[n * 64 + lane] = v / nrm;
}

// ---------------- kernel 1: h = x @ W_proj + b  (fp32 GEMM) ----------------
// M=16384 tokens, N=64, K=2048. Block: 256 thr, tile 64 tok x 64 dim, K-tile 64.
__global__ __launch_bounds__(256) void k_proj(const float* __restrict__ x,
                                              const float* __restrict__ W,
                                              const float* __restrict__ bias,
                                              float* __restrict__ h) {
  __shared__ float4 ldsX[2][64 * 17];   // [tok][17 float4] (68-float stride, 16B aligned rows)
  __shared__ float4 ldsW[2][64 * 16];   // [k][16 float4]

  int tid = threadIdx.x;
  int tx = tid & 15;          // dim quad 0..15
  int ty = tid >> 4;          // 0..15
  int ty4 = (ty & 3) * 4;     // compute row group uses ty in 0..3 per wave? no: thread tile below
  // thread tile: 4 tokens x 4 dims; token rows ty*4..ty*4+3 would need ty 0..15 -> 64 rows
  ty4 = ty * 4;               // 0..60
  size_t t0 = (size_t)blockIdx.x * 64;

  int srow = ty;              // staging row 0..15 (+r*16)
  int scol = tx * 4;

  float4 xr[4], wr[4];
  float acc[4][4] = {{0.f}};

  const float* xbase = x + t0 * DD;

  // prologue: load K-tile 0
#pragma unroll
  for (int r = 0; r < 4; ++r) {
    xr[r] = *(const float4*)(xbase + (size_t)(srow + r * 16) * DD + scol);
    wr[r] = *(const float4*)(W + (size_t)(srow + r * 16) * 64 + scol);
  }
#pragma unroll
  for (int r = 0; r < 4; ++r) {
    ldsX[0][(srow + r * 16) * 17 + tx] = xr[r];
    ldsW[0][(srow + r * 16) * 16 + tx] = wr[r];
  }
  __syncthreads();

  for (int kt = 0; kt < 32; ++kt) {
    int cur = kt & 1;
    if (kt < 31) {
      const float* xp = xbase + (kt + 1) * 64;
      const float* wp = W + (size_t)(kt + 1) * 64 * 64;
#pragma unroll
      for (int r = 0; r < 4; ++r) {
        xr[r] = *(const float4*)(xp + (size_t)(srow + r * 16) * DD + scol);
        wr[r] = *(const float4*)(wp + (size_t)(srow + r * 16) * 64 + scol);
      }
    }
    // compute on buf cur
#pragma unroll
    for (int kq = 0; kq < 16; ++kq) {
      float4 wv[4];
#pragma unroll
      for (int r = 0; r < 4; ++r) wv[r] = ldsW[cur][(kq * 4 + r) * 16 + tx];
#pragma unroll
      for (int j = 0; j < 4; ++j) {
        float4 xv = ldsX[cur][(ty4 + j) * 17 + kq];
        acc[j][0] = fmaf(xv.x, wv[0].x, acc[j][0]);
        acc[j][1] = fmaf(xv.x, wv[0].y, acc[j][1]);
        acc[j][2] = fmaf(xv.x, wv[0].z, acc[j][2]);
        acc[j][3] = fmaf(xv.x, wv[0].w, acc[j][3]);
        acc[j][0] = fmaf(xv.y, wv[1].x, acc[j][0]);
        acc[j][1] = fmaf(xv.y, wv[1].y, acc[j][1]);
        acc[j][2] = fmaf(xv.y, wv[1].z, acc[j][2]);
        acc[j][3] = fmaf(xv.y, wv[1].w, acc[j][3]);
        acc[j][0] = fmaf(xv.z, wv[2].x, acc[j][0]);
        acc[j][1] = fmaf(xv.z, wv[2].y, acc[j][1]);
        acc[j][2] = fmaf(xv.z, wv[2].z, acc[j][2]);
        acc[j][3] = fmaf(xv.z, wv[2].w, acc[j][3]);
        acc[j][0] = fmaf(xv.w, wv[3].x, acc[j][0]);
        acc[j][1] = fmaf(xv.w, wv[3].y, acc[j][1]);
        acc[j][2] = fmaf(xv.w, wv[3].z, acc[j][2]);
        acc[j][3] = fmaf(xv.w, wv[3].w, acc[j][3]);
      }
    }
    if (kt < 31) {
      __syncthreads();   // everyone done reading buf cur^1 (last iter) before overwrite
#pragma unroll
      for (int r = 0; r < 4; ++r) {
        ldsX[cur ^ 1][(srow + r * 16) * 17 + tx] = xr[r];
        ldsW[cur ^ 1][(srow + r * 16) * 16 + tx] = wr[r];
      }
      __syncthreads();   // buf cur^1 ready
    }
  }

  float4 b4 = *(const float4*)(bias + tx * 4);
#pragma unroll
  for (int j = 0; j < 4; ++j) {
    float4 o;
    o.x = acc[j][0] + b4.x;
    o.y = acc[j][1] + b4.y;
    o.z = acc[j][2] + b4.z;
    o.w = acc[j][3] + b4.w;
    *(float4*)(h + (t0 + ty4 + j) * 64 + tx * 4) = o;
  }
}

// ---------------- kernel 2: logits -> softmax -> importance pooling ----------------
// One block (512 thr) = one neuron group (512 neurons); lane keeps its neuron's
// embedding in registers. grid = 3 groups * 4 batch * NBB token-blocks.
__global__ __launch_bounds__(512) void k_pref(const float* __restrict__ h,
                                              const float* __restrict__ embn,
                                              const float* __restrict__ imp,
                                              float* __restrict__ partials) {
  int bid = blockIdx.x;
  int g = bid / (BB * NBB);
  int rem = bid % (BB * NBB);
  int b = rem / NBB;
  int nb = rem % NBB;
  int tid = threadIdx.x;
  int wave = tid >> 6, lane = tid & 63;

  __shared__ float red[2][8];

  float4 e[16];
  const float4* ebase = (const float4*)embn + (size_t)(g * 512 + tid) * 16;
#pragma unroll
  for (int q = 0; q < 16; ++q) e[q] = ebase[q];

  int s0 = nb * TPB;
  int s1 = s0 + TPB; if (s1 > SS) s1 = SS;

  float dense = 0.f;
  int par = 0;
  for (int s = s0; s < s1; ++s) {
    size_t token = (size_t)b * SS + s;
    const float4* hrow = (const float4*)(h + token * 64);   // uniform -> scalar loads
    float acc = 0.f;
#pragma unroll
    for (int q = 0; q < 16; ++q) {
      float4 hv = hrow[q];
      acc = fmaf(hv.x, e[q].x, acc);
      acc = fmaf(hv.y, e[q].y, acc);
      acc = fmaf(hv.z, e[q].z, acc);
      acc = fmaf(hv.w, e[q].w, acc);
    }
    float ex = __expf(acc);      // logits small (~N(0,1)); max-subtract unnecessary
    float zs = ex;
#pragma unroll
    for (int off = 32; off; off >>= 1) zs += __shfl_xor(zs, off, 64);
    if (lane == 0) red[par][wave] = zs;
    __syncthreads();
    float Z = red[par][0] + red[par][1] + red[par][2] + red[par][3] +
              red[par][4] + red[par][5] + red[par][6] + red[par][7];
    dense += imp[token] * ex / Z;
    par ^= 1;
  }
  partials[((size_t)(g * BB + b) * NBB + nb) * 512 + tid] = dense;
}

// ---------------- kernel 3: reduce partials + top-k + renormalize ----------------
__global__ __launch_bounds__(512) void k_topk(const float* __restrict__ partials,
                                              float* __restrict__ out) {
  int g = blockIdx.x >> 2;   // 0..2
  int b = blockIdx.x & 3;
  int tid = threadIdx.x;     // neuron 0..511
  int wave = tid >> 6, lane = tid & 63;

  __shared__ float lv[8][8];
  __shared__ int li[8][8];

  float dense = 0.f;
  const float* p = partials + (size_t)(g * BB + b) * NBB * 512 + tid;
  for (int nb = 0; nb < NBB; ++nb) dense += p[nb * 512];

  int K = (g == 0) ? 8 : (g == 1) ? 4 : 6;
  float val = dense;
  float ssum = 0.f;
  int sel = 0;
  for (int it = 0; it < K; ++it) {
    float v = val;
    int idx = tid;
#pragma unroll
    for (int off = 32; off; off >>= 1) {
      float ov = __shfl_xor(v, off, 64);
      int oi = __shfl_xor(idx, off, 64);
      if (ov > v || (ov == v && oi < idx)) { v = ov; idx = oi; }
    }
    if (lane == 0) { lv[it][wave] = v; li[it][wave] = idx; }
    __syncthreads();
    float mv = lv[it][0];
    int mi = li[it][0];
#pragma unroll
    for (int w = 1; w < 8; ++w) {
      float wv2 = lv[it][w];
      int wi = li[it][w];
      if (wv2 > mv || (wv2 == mv && wi < mi)) { mv = wv2; mi = wi; }
    }
    ssum += mv;
    if (tid == mi) { sel = 1; val = -3.0e38f; }
  }
  float o = sel ? dense / (ssum + 1e-8f) : 0.f;
  int row = (g == 0) ? 0 : (g == 1) ? 1 : 3;
  out[((size_t)row * BB + b) * 512 + tid] = o;
  if (g == 1) out[((size_t)2 * BB + b) * 512 + tid] = o;
}

extern "C" void kernel_launch(void* const* d_in, const int* in_sizes, int n_in,
                              void* d_out, int out_size, void* d_ws, size_t ws_size,
                              hipStream_t stream) {
  const float* x    = (const float*)d_in[0];
  const float* imp  = (const float*)d_in[1];
  const float* W    = (const float*)d_in[2];
  const float* bias = (const float*)d_in[3];
  const float* emb  = (const float*)d_in[4];
  float* out = (float*)d_out;

  char* ws = (char*)d_ws;
  float* embn     = (float*)ws;                          // 1536*64*4   = 393216 B
  float* h        = (float*)(ws + 393216);               // 16384*64*4  = 4 MiB
  float* partials = (float*)(ws + 393216 + 4194304);     // 12*42*512*4 = 1032192 B

  hipLaunchKernelGGL(k_norm, dim3(384), dim3(256), 0, stream, emb, embn);
  hipLaunchKernelGGL(k_proj, dim3(256), dim3(256), 0, stream, x, W, bias, h);
  hipLaunchKernelGGL(k_pref, dim3(3 * BB * NBB), dim3(512), 0, stream, h, embn, imp, partials);
  hipLaunchKernelGGL(k_topk, dim3(12), dim3(512), 0, stream, partials, out);
}

// Round 2
// 338.631 us; speedup vs baseline: 1.1349x; 1.1349x over previous
//
#include <hip/hip_runtime.h>

#define NTOT 1536
#define DD 2048
#define BB 4
#define SS 4096
#define NBB 32          // partial blocks per (group,b)
#define TPB 128         // 4096/32

typedef __attribute__((ext_vector_type(8))) short bf16x8;
typedef __attribute__((ext_vector_type(4))) float f32x4;

// ---------------- kernel 0: normalize neuron_emb rows ----------------
__global__ __launch_bounds__(256) void k_norm(const float* __restrict__ emb,
                                              float* __restrict__ out) {
  int wave = threadIdx.x >> 6;
  int lane = threadIdx.x & 63;
  int n = blockIdx.x * 4 + wave;          // grid 384 * 4 = 1536 exactly
  float v = emb[n * 64 + lane];
  float ss = v * v;
#pragma unroll
  for (int off = 32; off; off >>= 1) ss += __shfl_xor(ss, off, 64);
  float nrm = fmaxf(sqrtf(ss), 1e-12f);
  out[n * 64 + lane] = v / nrm;
}

// ---------------- kernel 0b: W -> hi/lo bf16 images, k-tiled + swizzled ----
// image layout per k-tile (8 KB): row n (0..63) of 128 B; 8 slots of 16 B;
// phys slot p holds logical slot s = p ^ (n&7); slot s covers k = s*8..s*8+7.
__global__ __launch_bounds__(256) void k_prepw(const float* __restrict__ W,
                                               short* __restrict__ imgH,
                                               short* __restrict__ imgL) {
  int kt = blockIdx.x;
  for (int idx = threadIdx.x; idx < 4096; idx += 256) {
    int n = idx & 63;
    int q = idx >> 6;          // 0..63
    int p = q >> 3;            // phys slot
    int e = q & 7;
    int s = p ^ (n & 7);       // logical slot
    int k = kt * 64 + s * 8 + e;
    float v = W[k * 64 + n];
    unsigned u = __float_as_uint(v);
    short hi = (short)(u >> 16);
    float hf = __uint_as_float(u & 0xffff0000u);
    float r = v - hf;
    short lo = (short)(__float_as_uint(r) >> 16);
    int flat = kt * 4096 + n * 64 + p * 8 + e;
    imgH[flat] = hi;
    imgL[flat] = lo;
  }
}

// ---------------- kernel 1: h = x @ W + b via hi/lo bf16 MFMA ----------------
// M=16384, N=64, K=2048. Block: 128 thr (2 waves), tile 32 tok x 64 n, K-tile 64.
// Wave w handles tokens w*16..w*16+15, all 64 n (4 fragments of 16).
__device__ __forceinline__ void split8(float4 a, float4 b, bf16x8& hi, bf16x8& lo) {
  float v[8] = {a.x, a.y, a.z, a.w, b.x, b.y, b.z, b.w};
#pragma unroll
  for (int i = 0; i < 8; ++i) {
    unsigned u = __float_as_uint(v[i]);
    hi[i] = (short)(u >> 16);
    float hf = __uint_as_float(u & 0xffff0000u);
    float r = v[i] - hf;
    lo[i] = (short)(__float_as_uint(r) >> 16);
  }
}

__global__ __launch_bounds__(128, 3) void k_proj(const float* __restrict__ x,
                                                 const float* __restrict__ imgHf,
                                                 const float* __restrict__ imgLf,
                                                 const float* __restrict__ bias,
                                                 float* __restrict__ h) {
  __shared__ float XAs[2][2048];   // [tok 0..31][64 k] fp32, swizzled slots
  __shared__ short BHs[2][4096];   // bf16 hi image tile (pre-swizzled)
  __shared__ short BLs[2][4096];

  int tid = threadIdx.x;
  int w = tid >> 6;
  int l = tid & 63;
  size_t t0 = (size_t)blockIdx.x * 32;

  int stok = tid >> 4;       // 0..7
  int sslot = tid & 15;      // logical slot (f4 of k)

  float4 xr[4], bhr[4], blr[4];
  f32x4 acc[4];
#pragma unroll
  for (int i = 0; i < 4; ++i) acc[i] = (f32x4){0.f, 0.f, 0.f, 0.f};

  const float4* imgH4 = (const float4*)imgHf;
  const float4* imgL4 = (const float4*)imgLf;

#define LOADT(KT)                                                                  \
  {                                                                                \
    _Pragma("unroll") for (int c = 0; c < 4; ++c) {                                \
      int tok = c * 8 + stok;                                                      \
      xr[c] = *(const float4*)(x + (t0 + tok) * DD + (KT) * 64 + sslot * 4);       \
      bhr[c] = imgH4[(KT) * 512 + c * 128 + tid];                                  \
      blr[c] = imgL4[(KT) * 512 + c * 128 + tid];                                  \
    }                                                                              \
  }

#define WRITET(DB)                                                                 \
  {                                                                                \
    _Pragma("unroll") for (int c = 0; c < 4; ++c) {                                \
      int tok = c * 8 + stok;                                                      \
      *(float4*)(&XAs[DB][tok * 64 + ((sslot ^ (tok & 7)) << 2)]) = xr[c];         \
      *(float4*)(&BHs[DB][c * 1024 + tid * 8]) = bhr[c];                           \
      *(float4*)(&BLs[DB][c * 1024 + tid * 8]) = blr[c];                           \
    }                                                                              \
  }

  LOADT(0);
  WRITET(0);
  __syncthreads();

  int db = 0;
  for (int kt = 0; kt < 32; ++kt) {
    if (kt < 31) LOADT(kt + 1);

    int row = w * 16 + (l & 15);       // block-local token row for A-frag
#pragma unroll
    for (int ks = 0; ks < 2; ++ks) {
      int s0 = ks * 8 + (l >> 4) * 2;
      float4 xa = *(const float4*)(&XAs[db][row * 64 + ((s0 ^ (row & 7)) << 2)]);
      float4 xb = *(const float4*)(&XAs[db][row * 64 + (((s0 + 1) ^ (row & 7)) << 2)]);
      bf16x8 ahi, alo;
      split8(xa, xb, ahi, alo);
#pragma unroll
      for (int nf = 0; nf < 4; ++nf) {
        int n = nf * 16 + (l & 15);
        int p = (ks * 4 + (l >> 4)) ^ (n & 7);
        bf16x8 bh = *(const bf16x8*)(&BHs[db][n * 64 + p * 8]);
        bf16x8 bl = *(const bf16x8*)(&BLs[db][n * 64 + p * 8]);
        acc[nf] = __builtin_amdgcn_mfma_f32_16x16x32_bf16(ahi, bh, acc[nf], 0, 0, 0);
        acc[nf] = __builtin_amdgcn_mfma_f32_16x16x32_bf16(alo, bh, acc[nf], 0, 0, 0);
        acc[nf] = __builtin_amdgcn_mfma_f32_16x16x32_bf16(ahi, bl, acc[nf], 0, 0, 0);
      }
    }

    if (kt < 31) WRITET(db ^ 1);
    __syncthreads();
    db ^= 1;
  }

  // epilogue: D row=(l>>4)*4+j (token-local), col=l&15 (n-local)
#pragma unroll
  for (int nf = 0; nf < 4; ++nf) {
    int n = nf * 16 + (l & 15);
    float bv = bias[n];
#pragma unroll
    for (int j = 0; j < 4; ++j) {
      size_t tok = t0 + w * 16 + (l >> 4) * 4 + j;
      h[tok * 64 + n] = acc[nf][j] + bv;
    }
  }
#undef LOADT
#undef WRITET
}

// ---------------- kernel 2: logits -> softmax -> importance pooling ----------------
// One block (512 thr) = one neuron group; 4 tokens per barrier round.
__global__ __launch_bounds__(512) void k_pref(const float* __restrict__ h,
                                              const float* __restrict__ embn,
                                              const float* __restrict__ imp,
                                              float* __restrict__ partials) {
  int bid = blockIdx.x;
  int g = bid / (BB * NBB);
  int rem = bid % (BB * NBB);
  int b = rem / NBB;
  int nb = rem % NBB;
  int tid = threadIdx.x;
  int wave = tid >> 6, lane = tid & 63;

  __shared__ float red[2][4][8];

  float4 e[16];
  const float4* ebase = (const float4*)embn + (size_t)(g * 512 + tid) * 16;
#pragma unroll
  for (int q = 0; q < 16; ++q) e[q] = ebase[q];

  float dense = 0.f;
  int par = 0;
  int sbase = nb * TPB;
  for (int s0 = sbase; s0 < sbase + TPB; s0 += 4) {
    const float4* h0 = (const float4*)(h + ((size_t)b * SS + s0) * 64);
    float a0 = 0.f, a1 = 0.f, a2 = 0.f, a3 = 0.f;
#pragma unroll 4
    for (int q = 0; q < 16; ++q) {
      float4 h00 = h0[q], h1 = h0[16 + q], h2 = h0[32 + q], h3 = h0[48 + q];
      float4 eq = e[q];
      a0 = fmaf(h00.x, eq.x, a0); a0 = fmaf(h00.y, eq.y, a0);
      a0 = fmaf(h00.z, eq.z, a0); a0 = fmaf(h00.w, eq.w, a0);
      a1 = fmaf(h1.x, eq.x, a1); a1 = fmaf(h1.y, eq.y, a1);
      a1 = fmaf(h1.z, eq.z, a1); a1 = fmaf(h1.w, eq.w, a1);
      a2 = fmaf(h2.x, eq.x, a2); a2 = fmaf(h2.y, eq.y, a2);
      a2 = fmaf(h2.z, eq.z, a2); a2 = fmaf(h2.w, eq.w, a2);
      a3 = fmaf(h3.x, eq.x, a3); a3 = fmaf(h3.y, eq.y, a3);
      a3 = fmaf(h3.z, eq.z, a3); a3 = fmaf(h3.w, eq.w, a3);
    }
    float ex0 = __expf(a0), ex1 = __expf(a1), ex2 = __expf(a2), ex3 = __expf(a3);
    float z0 = ex0, z1 = ex1, z2 = ex2, z3 = ex3;
#pragma unroll
    for (int off = 32; off; off >>= 1) {
      z0 += __shfl_xor(z0, off, 64);
      z1 += __shfl_xor(z1, off, 64);
      z2 += __shfl_xor(z2, off, 64);
      z3 += __shfl_xor(z3, off, 64);
    }
    if (lane == 0) {
      red[par][0][wave] = z0; red[par][1][wave] = z1;
      red[par][2][wave] = z2; red[par][3][wave] = z3;
    }
    __syncthreads();
    float Z0 = 0.f, Z1 = 0.f, Z2 = 0.f, Z3 = 0.f;
#pragma unroll
    for (int ww = 0; ww < 8; ++ww) {
      Z0 += red[par][0][ww]; Z1 += red[par][1][ww];
      Z2 += red[par][2][ww]; Z3 += red[par][3][ww];
    }
    size_t ib = (size_t)b * SS + s0;
    dense += imp[ib] * ex0 / Z0 + imp[ib + 1] * ex1 / Z1 +
             imp[ib + 2] * ex2 / Z2 + imp[ib + 3] * ex3 / Z3;
    par ^= 1;
  }
  partials[((size_t)(g * BB + b) * NBB + nb) * 512 + tid] = dense;
}

// ---------------- kernel 3: reduce partials + top-k + renormalize ----------------
__global__ __launch_bounds__(512) void k_topk(const float* __restrict__ partials,
                                              float* __restrict__ out) {
  int g = blockIdx.x >> 2;   // 0..2
  int b = blockIdx.x & 3;
  int tid = threadIdx.x;     // neuron 0..511
  int wave = tid >> 6, lane = tid & 63;

  __shared__ float lv[8][8];
  __shared__ int li[8][8];

  float dense = 0.f;
  const float* p = partials + (size_t)(g * BB + b) * NBB * 512 + tid;
  for (int nb = 0; nb < NBB; ++nb) dense += p[nb * 512];

  int K = (g == 0) ? 8 : (g == 1) ? 4 : 6;
  float val = dense;
  float ssum = 0.f;
  int sel = 0;
  for (int it = 0; it < K; ++it) {
    float v = val;
    int idx = tid;
#pragma unroll
    for (int off = 32; off; off >>= 1) {
      float ov = __shfl_xor(v, off, 64);
      int oi = __shfl_xor(idx, off, 64);
      if (ov > v || (ov == v && oi < idx)) { v = ov; idx = oi; }
    }
    if (lane == 0) { lv[it][wave] = v; li[it][wave] = idx; }
    __syncthreads();
    float mv = lv[it][0];
    int mi = li[it][0];
#pragma unroll
    for (int ww = 1; ww < 8; ++ww) {
      float wv2 = lv[it][ww];
      int wi = li[it][ww];
      if (wv2 > mv || (wv2 == mv && wi < mi)) { mv = wv2; mi = wi; }
    }
    ssum += mv;
    if (tid == mi) { sel = 1; val = -3.0e38f; }
  }
  float o = sel ? dense / (ssum + 1e-8f) : 0.f;
  int row = (g == 0) ? 0 : (g == 1) ? 1 : 3;
  out[((size_t)row * BB + b) * 512 + tid] = o;
  if (g == 1) out[((size_t)2 * BB + b) * 512 + tid] = o;
}

extern "C" void kernel_launch(void* const* d_in, const int* in_sizes, int n_in,
                              void* d_out, int out_size, void* d_ws, size_t ws_size,
                              hipStream_t stream) {
  const float* x    = (const float*)d_in[0];
  const float* imp  = (const float*)d_in[1];
  const float* W    = (const float*)d_in[2];
  const float* bias = (const float*)d_in[3];
  const float* emb  = (const float*)d_in[4];
  float* out = (float*)d_out;

  char* ws = (char*)d_ws;
  float* embn     = (float*)ws;                           // 1536*64*4   = 393216 B
  float* h        = (float*)(ws + 393216);                // 16384*64*4  = 4 MiB
  float* partials = (float*)(ws + 4587520);               // 12*32*512*4 = 786432 B
  short* imgH     = (short*)(ws + 5373952);               // 32*4096*2   = 262144 B
  short* imgL     = (short*)(ws + 5636096);               // 262144 B

  hipLaunchKernelGGL(k_norm, dim3(384), dim3(256), 0, stream, emb, embn);
  hipLaunchKernelGGL(k_prepw, dim3(32), dim3(256), 0, stream, W, imgH, imgL);
  hipLaunchKernelGGL(k_proj, dim3(512), dim3(128), 0, stream,
                     x, (const float*)imgH, (const float*)imgL, bias, h);
  hipLaunchKernelGGL(k_pref, dim3(3 * BB * NBB), dim3(512), 0, stream, h, embn, imp, partials);
  hipLaunchKernelGGL(k_topk, dim3(12), dim3(512), 0, stream, partials, out);
}

// Round 3
// 236.782 us; speedup vs baseline: 1.6230x; 1.4301x over previous
//
#include <hip/hip_runtime.h>

#define NTOT 1536
#define DD 2048
#define BB 4
#define SS 4096
#define NBB 42          // partial blocks per (group,b)
#define TPB 98          // ceil(4096/42)
#define NTILE 7         // 7*16 = 112 >= 98 token slots per block

typedef __attribute__((ext_vector_type(8))) short bf16x8;
typedef __attribute__((ext_vector_type(4))) float f32x4;

__device__ __forceinline__ void split1(float v, unsigned short& hi, unsigned short& lo) {
  unsigned u = __float_as_uint(v);
  hi = (unsigned short)(u >> 16);
  float hf = __uint_as_float(u & 0xffff0000u);
  float r = v - hf;
  lo = (unsigned short)(__float_as_uint(r) >> 16);
}

// ---------------- kernel 0: normalize neuron_emb rows -> hi/lo bf16 ----------------
__global__ __launch_bounds__(256) void k_prep_emb(const float* __restrict__ emb,
                                                  short* __restrict__ eH,
                                                  short* __restrict__ eL) {
  int wave = threadIdx.x >> 6;
  int lane = threadIdx.x & 63;
  int n = blockIdx.x * 4 + wave;          // grid 384 * 4 = 1536 exactly
  float v = emb[n * 64 + lane];
  float ss = v * v;
#pragma unroll
  for (int off = 32; off; off >>= 1) ss += __shfl_xor(ss, off, 64);
  float nrm = fmaxf(sqrtf(ss), 1e-12f);
  float nv = v / nrm;
  unsigned short hi, lo;
  split1(nv, hi, lo);
  eH[n * 64 + lane] = (short)hi;
  eL[n * 64 + lane] = (short)lo;
}

// ---------------- kernel 0b: W -> hi/lo bf16 images, k-tiled + swizzled ----
__global__ __launch_bounds__(256) void k_prepw(const float* __restrict__ W,
                                               short* __restrict__ imgH,
                                               short* __restrict__ imgL) {
  int kt = blockIdx.x;
  for (int idx = threadIdx.x; idx < 4096; idx += 256) {
    int n = idx & 63;
    int q = idx >> 6;          // 0..63
    int p = q >> 3;            // phys slot
    int e = q & 7;
    int s = p ^ (n & 7);       // logical slot
    int k = kt * 64 + s * 8 + e;
    float v = W[k * 64 + n];
    unsigned short hi, lo;
    split1(v, hi, lo);
    int flat = kt * 4096 + n * 64 + p * 8 + e;
    imgH[flat] = (short)hi;
    imgL[flat] = (short)lo;
  }
}

// ---------------- kernel 1: h = x @ W + b via hi/lo bf16 MFMA -> hi/lo h ----------
__device__ __forceinline__ void split8(float4 a, float4 b, bf16x8& hi, bf16x8& lo) {
  float v[8] = {a.x, a.y, a.z, a.w, b.x, b.y, b.z, b.w};
#pragma unroll
  for (int i = 0; i < 8; ++i) {
    unsigned u = __float_as_uint(v[i]);
    hi[i] = (short)(u >> 16);
    float hf = __uint_as_float(u & 0xffff0000u);
    float r = v[i] - hf;
    lo[i] = (short)(__float_as_uint(r) >> 16);
  }
}

__global__ __launch_bounds__(128, 3) void k_proj(const float* __restrict__ x,
                                                 const float* __restrict__ imgHf,
                                                 const float* __restrict__ imgLf,
                                                 const float* __restrict__ bias,
                                                 short* __restrict__ hH,
                                                 short* __restrict__ hL) {
  __shared__ float XAs[2][2048];   // [tok 0..31][64 k] fp32, swizzled slots
  __shared__ short BHs[2][4096];   // bf16 hi image tile (pre-swizzled)
  __shared__ short BLs[2][4096];

  int tid = threadIdx.x;
  int w = tid >> 6;
  int l = tid & 63;
  size_t t0 = (size_t)blockIdx.x * 32;

  int stok = tid >> 4;       // 0..7
  int sslot = tid & 15;      // logical slot (f4 of k)

  float4 xr[4], bhr[4], blr[4];
  f32x4 acc[4];
#pragma unroll
  for (int i = 0; i < 4; ++i) acc[i] = (f32x4){0.f, 0.f, 0.f, 0.f};

  const float4* imgH4 = (const float4*)imgHf;
  const float4* imgL4 = (const float4*)imgLf;

#define LOADT(KT)                                                                  \
  {                                                                                \
    _Pragma("unroll") for (int c = 0; c < 4; ++c) {                                \
      int tok = c * 8 + stok;                                                      \
      xr[c] = *(const float4*)(x + (t0 + tok) * DD + (KT) * 64 + sslot * 4);       \
      bhr[c] = imgH4[(KT) * 512 + c * 128 + tid];                                  \
      blr[c] = imgL4[(KT) * 512 + c * 128 + tid];                                  \
    }                                                                              \
  }

#define WRITET(DB)                                                                 \
  {                                                                                \
    _Pragma("unroll") for (int c = 0; c < 4; ++c) {                                \
      int tok = c * 8 + stok;                                                      \
      *(float4*)(&XAs[DB][tok * 64 + ((sslot ^ (tok & 7)) << 2)]) = xr[c];         \
      *(float4*)(&BHs[DB][c * 1024 + tid * 8]) = bhr[c];                           \
      *(float4*)(&BLs[DB][c * 1024 + tid * 8]) = blr[c];                           \
    }                                                                              \
  }

  LOADT(0);
  WRITET(0);
  __syncthreads();

  int db = 0;
  for (int kt = 0; kt < 32; ++kt) {
    if (kt < 31) LOADT(kt + 1);

    int row = w * 16 + (l & 15);       // block-local token row for A-frag
#pragma unroll
    for (int ks = 0; ks < 2; ++ks) {
      int s0 = ks * 8 + (l >> 4) * 2;
      float4 xa = *(const float4*)(&XAs[db][row * 64 + ((s0 ^ (row & 7)) << 2)]);
      float4 xb = *(const float4*)(&XAs[db][row * 64 + (((s0 + 1) ^ (row & 7)) << 2)]);
      bf16x8 ahi, alo;
      split8(xa, xb, ahi, alo);
#pragma unroll
      for (int nf = 0; nf < 4; ++nf) {
        int n = nf * 16 + (l & 15);
        int p = (ks * 4 + (l >> 4)) ^ (n & 7);
        bf16x8 bh = *(const bf16x8*)(&BHs[db][n * 64 + p * 8]);
        bf16x8 bl = *(const bf16x8*)(&BLs[db][n * 64 + p * 8]);
        acc[nf] = __builtin_amdgcn_mfma_f32_16x16x32_bf16(ahi, bh, acc[nf], 0, 0, 0);
        acc[nf] = __builtin_amdgcn_mfma_f32_16x16x32_bf16(alo, bh, acc[nf], 0, 0, 0);
        acc[nf] = __builtin_amdgcn_mfma_f32_16x16x32_bf16(ahi, bl, acc[nf], 0, 0, 0);
      }
    }

    if (kt < 31) WRITET(db ^ 1);
    __syncthreads();
    db ^= 1;
  }

  // epilogue: token=(l>>4)*4+j (wave-local), n = nf*16 + (l&15); emit hi/lo bf16
#pragma unroll
  for (int nf = 0; nf < 4; ++nf) {
    int n = nf * 16 + (l & 15);
    float bv = bias[n];
#pragma unroll
    for (int j = 0; j < 4; ++j) {
      size_t tok = t0 + w * 16 + (l >> 4) * 4 + j;
      float v = acc[nf][j] + bv;
      unsigned short hi, lo;
      split1(v, hi, lo);
      hH[tok * 64 + n] = (short)hi;
      hL[tok * 64 + n] = (short)lo;
    }
  }
#undef LOADT
#undef WRITET
}

// ---------------- kernel 2: MFMA logits -> softmax -> importance pooling ----------
// Block: 512 thr (8 waves) = one group of 512 neurons; wave owns 64 neurons with
// B-fragments resident in registers; loop over 7 tiles of 16 tokens.
__global__ __launch_bounds__(512, 4) void k_pref(const short* __restrict__ hH,
                                                 const short* __restrict__ hL,
                                                 const short* __restrict__ eH,
                                                 const short* __restrict__ eL,
                                                 const float* __restrict__ imp,
                                                 float* __restrict__ partials) {
  int bid = blockIdx.x;
  int g = bid / (BB * NBB);
  int rem = bid % (BB * NBB);
  int b = rem / NBB;
  int nb = rem % NBB;
  int tid = threadIdx.x;
  int w = tid >> 6;
  int l = tid & 63;
  int col = l & 15;
  int q = l >> 4;

  __shared__ float zred[2][8][16];

  // B-fragments: neuron n = g*512 + w*64 + nf*16 + col; k = ks*32 + q*8 + e
  bf16x8 BH[4][2], BL[4][2];
  {
    const short* eHg = eH + ((size_t)(g * 512 + w * 64 + col)) * 64 + q * 8;
    const short* eLg = eL + ((size_t)(g * 512 + w * 64 + col)) * 64 + q * 8;
#pragma unroll
    for (int nf = 0; nf < 4; ++nf) {
#pragma unroll
      for (int ks = 0; ks < 2; ++ks) {
        BH[nf][ks] = *(const bf16x8*)(eHg + nf * 1024 + ks * 32);
        BL[nf][ks] = *(const bf16x8*)(eLg + nf * 1024 + ks * 32);
      }
    }
  }

  int s0 = nb * TPB;
  int slim = s0 + TPB; if (slim > SS) slim = SS;
  float wsum[4] = {0.f, 0.f, 0.f, 0.f};
  int par = 0;

  for (int tile = 0; tile < NTILE; ++tile) {
    int tbase = s0 + tile * 16;
    int arow = tbase + col; if (arow > SS - 1) arow = SS - 1;
    size_t hoff = ((size_t)b * SS + arow) * 64;
    bf16x8 AH0 = *(const bf16x8*)(hH + hoff + q * 8);
    bf16x8 AH1 = *(const bf16x8*)(hH + hoff + 32 + q * 8);
    bf16x8 AL0 = *(const bf16x8*)(hL + hoff + q * 8);
    bf16x8 AL1 = *(const bf16x8*)(hL + hoff + 32 + q * 8);

    f32x4 acc[4];
#pragma unroll
    for (int nf = 0; nf < 4; ++nf) acc[nf] = (f32x4){0.f, 0.f, 0.f, 0.f};
#pragma unroll
    for (int nf = 0; nf < 4; ++nf) {
      acc[nf] = __builtin_amdgcn_mfma_f32_16x16x32_bf16(AH0, BH[nf][0], acc[nf], 0, 0, 0);
      acc[nf] = __builtin_amdgcn_mfma_f32_16x16x32_bf16(AL0, BH[nf][0], acc[nf], 0, 0, 0);
      acc[nf] = __builtin_amdgcn_mfma_f32_16x16x32_bf16(AH0, BL[nf][0], acc[nf], 0, 0, 0);
      acc[nf] = __builtin_amdgcn_mfma_f32_16x16x32_bf16(AH1, BH[nf][1], acc[nf], 0, 0, 0);
      acc[nf] = __builtin_amdgcn_mfma_f32_16x16x32_bf16(AL1, BH[nf][1], acc[nf], 0, 0, 0);
      acc[nf] = __builtin_amdgcn_mfma_f32_16x16x32_bf16(AH1, BL[nf][1], acc[nf], 0, 0, 0);
    }

    // exp + per-token partial Z over this wave's 64 neurons
    float e0[4], e1[4], e2[4], e3[4];
    float zp[4];
#pragma unroll
    for (int j = 0; j < 4; ++j) {
      e0[j] = __expf(acc[0][j]);
      e1[j] = __expf(acc[1][j]);
      e2[j] = __expf(acc[2][j]);
      e3[j] = __expf(acc[3][j]);
      zp[j] = e0[j] + e1[j] + e2[j] + e3[j];
    }
#pragma unroll
    for (int off = 1; off <= 8; off <<= 1) {
#pragma unroll
      for (int j = 0; j < 4; ++j) zp[j] += __shfl_xor(zp[j], off, 64);
    }
    // exchange across waves (token t16 = q*4 + j handled by this lane-group)
    float zw = (col == 0) ? zp[0] : (col == 1) ? zp[1] : (col == 2) ? zp[2] : zp[3];
    if (col < 4) zred[par][w][q * 4 + col] = zw;
    __syncthreads();
    float r0, r1, r2, r3;
    {
#pragma unroll
      for (int j = 0; j < 4; ++j) {
        int t16 = q * 4 + j;
        float Z = 0.f;
#pragma unroll
        for (int ww = 0; ww < 8; ++ww) Z += zred[par][ww][t16];
        int s = tbase + t16;
        float iv = (s < slim) ? imp[(size_t)b * SS + s] : 0.f;
        float r = iv / Z;
        if (j == 0) r0 = r; else if (j == 1) r1 = r; else if (j == 2) r2 = r; else r3 = r;
      }
    }
    wsum[0] += e0[0] * r0 + e0[1] * r1 + e0[2] * r2 + e0[3] * r3;
    wsum[1] += e1[0] * r0 + e1[1] * r1 + e1[2] * r2 + e1[3] * r3;
    wsum[2] += e2[0] * r0 + e2[1] * r1 + e2[2] * r2 + e2[3] * r3;
    wsum[3] += e3[0] * r0 + e3[1] * r1 + e3[2] * r2 + e3[3] * r3;
    par ^= 1;
  }

  // sum over the 4 lane-groups (tokens) -> every lane holds the full token-sum
#pragma unroll
  for (int nf = 0; nf < 4; ++nf) {
    wsum[nf] += __shfl_xor(wsum[nf], 16, 64);
    wsum[nf] += __shfl_xor(wsum[nf], 32, 64);
  }
  if (q == 0) {
    size_t base = ((size_t)(g * BB + b) * NBB + nb) * 512 + w * 64;
#pragma unroll
    for (int nf = 0; nf < 4; ++nf) partials[base + nf * 16 + col] = wsum[nf];
  }
}

// ---------------- kernel 3: reduce partials + top-k + renormalize ----------------
__global__ __launch_bounds__(512) void k_topk(const float* __restrict__ partials,
                                              float* __restrict__ out) {
  int g = blockIdx.x >> 2;   // 0..2
  int b = blockIdx.x & 3;
  int tid = threadIdx.x;     // neuron 0..511
  int wave = tid >> 6, lane = tid & 63;

  __shared__ float lv[8][8];
  __shared__ int li[8][8];

  float dense = 0.f;
  const float* p = partials + (size_t)(g * BB + b) * NBB * 512 + tid;
  for (int nb = 0; nb < NBB; ++nb) dense += p[nb * 512];

  int K = (g == 0) ? 8 : (g == 1) ? 4 : 6;
  float val = dense;
  float ssum = 0.f;
  int sel = 0;
  for (int it = 0; it < K; ++it) {
    float v = val;
    int idx = tid;
#pragma unroll
    for (int off = 32; off; off >>= 1) {
      float ov = __shfl_xor(v, off, 64);
      int oi = __shfl_xor(idx, off, 64);
      if (ov > v || (ov == v && oi < idx)) { v = ov; idx = oi; }
    }
    if (lane == 0) { lv[wave][0] = v; li[wave][0] = idx; }
    __syncthreads();
    float mv = lv[0][0];
    int mi = li[0][0];
#pragma unroll
    for (int ww = 1; ww < 8; ++ww) {
      float wv2 = lv[ww][0];
      int wi = li[ww][0];
      if (wv2 > mv || (wv2 == mv && wi < mi)) { mv = wv2; mi = wi; }
    }
    ssum += mv;
    if (tid == mi) { sel = 1; val = -3.0e38f; }
    __syncthreads();
  }
  float o = sel ? dense / (ssum + 1e-8f) : 0.f;
  int row = (g == 0) ? 0 : (g == 1) ? 1 : 3;
  out[((size_t)row * BB + b) * 512 + tid] = o;
  if (g == 1) out[((size_t)2 * BB + b) * 512 + tid] = o;
}

extern "C" void kernel_launch(void* const* d_in, const int* in_sizes, int n_in,
                              void* d_out, int out_size, void* d_ws, size_t ws_size,
                              hipStream_t stream) {
  const float* x    = (const float*)d_in[0];
  const float* imp  = (const float*)d_in[1];
  const float* W    = (const float*)d_in[2];
  const float* bias = (const float*)d_in[3];
  const float* emb  = (const float*)d_in[4];
  float* out = (float*)d_out;

  char* ws = (char*)d_ws;
  short* imgH     = (short*)(ws + 0);          // 262144 B
  short* imgL     = (short*)(ws + 262144);     // 262144 B
  short* eH       = (short*)(ws + 524288);     // 196608 B
  short* eL       = (short*)(ws + 720896);     // 196608 B
  short* hH       = (short*)(ws + 917504);     // 2097152 B
  short* hL       = (short*)(ws + 3014656);    // 2097152 B
  float* partials = (float*)(ws + 5111808);    // 12*42*512*4 = 1032192 B

  hipLaunchKernelGGL(k_prep_emb, dim3(384), dim3(256), 0, stream, emb, eH, eL);
  hipLaunchKernelGGL(k_prepw, dim3(32), dim3(256), 0, stream, W, imgH, imgL);
  hipLaunchKernelGGL(k_proj, dim3(512), dim3(128), 0, stream,
                     x, (const float*)imgH, (const float*)imgL, bias, hH, hL);
  hipLaunchKernelGGL(k_pref, dim3(3 * BB * NBB), dim3(512), 0, stream,
                     hH, hL, eH, eL, imp, partials);
  hipLaunchKernelGGL(k_topk, dim3(12), dim3(512), 0, stream, partials, out);
}

// Round 4
// 171.966 us; speedup vs baseline: 2.2348x; 1.3769x over previous
//
#include <hip/hip_runtime.h>

#define NTOT 1536
#define DD 2048
#define BB 4
#define SS 4096
#define NBB 42          // partial blocks per (group,b)
#define TPB 98          // ceil(4096/42)
#define NTILE 7         // 7*16 = 112 >= 98 token slots per block

typedef __attribute__((ext_vector_type(8))) short bf16x8;
typedef __attribute__((ext_vector_type(4))) float f32x4;

__device__ __forceinline__ void split1(float v, unsigned short& hi, unsigned short& lo) {
  unsigned u = __float_as_uint(v);
  hi = (unsigned short)(u >> 16);
  float hf = __uint_as_float(u & 0xffff0000u);
  float r = v - hf;
  lo = (unsigned short)(__float_as_uint(r) >> 16);
}

// ---------------- kernel 0: normalize neuron_emb rows -> hi/lo bf16 ----------------
__global__ __launch_bounds__(256) void k_prep_emb(const float* __restrict__ emb,
                                                  short* __restrict__ eH,
                                                  short* __restrict__ eL) {
  int wave = threadIdx.x >> 6;
  int lane = threadIdx.x & 63;
  int n = blockIdx.x * 4 + wave;          // grid 384 * 4 = 1536 exactly
  float v = emb[n * 64 + lane];
  float ss = v * v;
#pragma unroll
  for (int off = 32; off; off >>= 1) ss += __shfl_xor(ss, off, 64);
  float nrm = fmaxf(sqrtf(ss), 1e-12f);
  float nv = v / nrm;
  unsigned short hi, lo;
  split1(nv, hi, lo);
  eH[n * 64 + lane] = (short)hi;
  eL[n * 64 + lane] = (short)lo;
}

// ---------------- kernel 0b: W -> hi/lo bf16 images, k-tiled + swizzled ----
__global__ __launch_bounds__(256) void k_prepw(const float* __restrict__ W,
                                               short* __restrict__ imgH,
                                               short* __restrict__ imgL) {
  int kt = blockIdx.x;
  for (int idx = threadIdx.x; idx < 4096; idx += 256) {
    int n = idx & 63;
    int q = idx >> 6;          // 0..63
    int p = q >> 3;            // phys slot
    int e = q & 7;
    int s = p ^ (n & 7);       // logical slot
    int k = kt * 64 + s * 8 + e;
    float v = W[k * 64 + n];
    unsigned short hi, lo;
    split1(v, hi, lo);
    int flat = kt * 4096 + n * 64 + p * 8 + e;
    imgH[flat] = (short)hi;
    imgL[flat] = (short)lo;
  }
}

// ---------------- kernel 1: h = x @ W + b via hi/lo bf16 MFMA -> hi/lo h ----------
__device__ __forceinline__ void split8(float4 a, float4 b, bf16x8& hi, bf16x8& lo) {
  float v[8] = {a.x, a.y, a.z, a.w, b.x, b.y, b.z, b.w};
#pragma unroll
  for (int i = 0; i < 8; ++i) {
    unsigned u = __float_as_uint(v[i]);
    hi[i] = (short)(u >> 16);
    float hf = __uint_as_float(u & 0xffff0000u);
    float r = v[i] - hf;
    lo[i] = (short)(__float_as_uint(r) >> 16);
  }
}

__global__ __launch_bounds__(128, 3) void k_proj(const float* __restrict__ x,
                                                 const float* __restrict__ imgHf,
                                                 const float* __restrict__ imgLf,
                                                 const float* __restrict__ bias,
                                                 short* __restrict__ hH,
                                                 short* __restrict__ hL) {
  __shared__ float XAs[2][2048];   // [tok 0..31][64 k] fp32, swizzled slots
  __shared__ short BHs[2][4096];   // bf16 hi image tile (pre-swizzled)
  __shared__ short BLs[2][4096];

  int tid = threadIdx.x;
  int w = tid >> 6;
  int l = tid & 63;
  size_t t0 = (size_t)blockIdx.x * 32;

  int stok = tid >> 4;       // 0..7
  int sslot = tid & 15;      // logical slot (f4 of k)

  float4 xr[4], bhr[4], blr[4];
  f32x4 acc[4];
#pragma unroll
  for (int i = 0; i < 4; ++i) acc[i] = (f32x4){0.f, 0.f, 0.f, 0.f};

  const float4* imgH4 = (const float4*)imgHf;
  const float4* imgL4 = (const float4*)imgLf;

#define LOADT(KT)                                                                  \
  {                                                                                \
    _Pragma("unroll") for (int c = 0; c < 4; ++c) {                                \
      int tok = c * 8 + stok;                                                      \
      xr[c] = *(const float4*)(x + (t0 + tok) * DD + (KT) * 64 + sslot * 4);       \
      bhr[c] = imgH4[(KT) * 512 + c * 128 + tid];                                  \
      blr[c] = imgL4[(KT) * 512 + c * 128 + tid];                                  \
    }                                                                              \
  }

#define WRITET(DB)                                                                 \
  {                                                                                \
    _Pragma("unroll") for (int c = 0; c < 4; ++c) {                                \
      int tok = c * 8 + stok;                                                      \
      *(float4*)(&XAs[DB][tok * 64 + ((sslot ^ (tok & 7)) << 2)]) = xr[c];         \
      *(float4*)(&BHs[DB][c * 1024 + tid * 8]) = bhr[c];                           \
      *(float4*)(&BLs[DB][c * 1024 + tid * 8]) = blr[c];                           \
    }                                                                              \
  }

  LOADT(0);
  WRITET(0);
  __syncthreads();

  int db = 0;
  for (int kt = 0; kt < 32; ++kt) {
    if (kt < 31) LOADT(kt + 1);

    int row = w * 16 + (l & 15);       // block-local token row for A-frag
#pragma unroll
    for (int ks = 0; ks < 2; ++ks) {
      int s0 = ks * 8 + (l >> 4) * 2;
      float4 xa = *(const float4*)(&XAs[db][row * 64 + ((s0 ^ (row & 7)) << 2)]);
      float4 xb = *(const float4*)(&XAs[db][row * 64 + (((s0 + 1) ^ (row & 7)) << 2)]);
      bf16x8 ahi, alo;
      split8(xa, xb, ahi, alo);
#pragma unroll
      for (int nf = 0; nf < 4; ++nf) {
        int n = nf * 16 + (l & 15);
        int p = (ks * 4 + (l >> 4)) ^ (n & 7);
        bf16x8 bh = *(const bf16x8*)(&BHs[db][n * 64 + p * 8]);
        bf16x8 bl = *(const bf16x8*)(&BLs[db][n * 64 + p * 8]);
        acc[nf] = __builtin_amdgcn_mfma_f32_16x16x32_bf16(ahi, bh, acc[nf], 0, 0, 0);
        acc[nf] = __builtin_amdgcn_mfma_f32_16x16x32_bf16(alo, bh, acc[nf], 0, 0, 0);
        acc[nf] = __builtin_amdgcn_mfma_f32_16x16x32_bf16(ahi, bl, acc[nf], 0, 0, 0);
      }
    }

    if (kt < 31) WRITET(db ^ 1);
    __syncthreads();
    db ^= 1;
  }

  // epilogue: token=(l>>4)*4+j (wave-local), n = nf*16 + (l&15); emit hi/lo bf16
#pragma unroll
  for (int nf = 0; nf < 4; ++nf) {
    int n = nf * 16 + (l & 15);
    float bv = bias[n];
#pragma unroll
    for (int j = 0; j < 4; ++j) {
      size_t tok = t0 + w * 16 + (l >> 4) * 4 + j;
      float v = acc[nf][j] + bv;
      unsigned short hi, lo;
      split1(v, hi, lo);
      hH[tok * 64 + n] = (short)hi;
      hL[tok * 64 + n] = (short)lo;
    }
  }
#undef LOADT
#undef WRITET
}

// ---------------- kernel 2: MFMA logits -> softmax -> importance pooling ----------
// Block: 512 thr (8 waves) = one group of 512 neurons; wave owns 64 neurons with
// B-fragments resident in registers; loop over 7 tiles of 16 tokens.
// launch_bounds(512,2): VGPR cap 256 — live state ~140 regs MUST NOT spill.
__global__ __launch_bounds__(512, 2) void k_pref(const short* __restrict__ hH,
                                                 const short* __restrict__ hL,
                                                 const short* __restrict__ eH,
                                                 const short* __restrict__ eL,
                                                 const float* __restrict__ imp,
                                                 float* __restrict__ partials) {
  int bid = blockIdx.x;
  int g = bid / (BB * NBB);
  int rem = bid % (BB * NBB);
  int b = rem / NBB;
  int nb = rem % NBB;
  int tid = threadIdx.x;
  int w = tid >> 6;
  int l = tid & 63;
  int col = l & 15;
  int q = l >> 4;

  __shared__ float zred[2][8][16];

  // B-fragments: neuron n = g*512 + w*64 + nf*16 + col; k = ks*32 + q*8 + e
  bf16x8 BH[4][2], BL[4][2];
  {
    const short* eHg = eH + ((size_t)(g * 512 + w * 64 + col)) * 64 + q * 8;
    const short* eLg = eL + ((size_t)(g * 512 + w * 64 + col)) * 64 + q * 8;
#pragma unroll
    for (int nf = 0; nf < 4; ++nf) {
#pragma unroll
      for (int ks = 0; ks < 2; ++ks) {
        BH[nf][ks] = *(const bf16x8*)(eHg + nf * 1024 + ks * 32);
        BL[nf][ks] = *(const bf16x8*)(eLg + nf * 1024 + ks * 32);
      }
    }
  }

  int s0 = nb * TPB;
  int slim = s0 + TPB; if (slim > SS) slim = SS;
  float wsum[4] = {0.f, 0.f, 0.f, 0.f};
  int par = 0;

  for (int tile = 0; tile < NTILE; ++tile) {
    int tbase = s0 + tile * 16;
    int arow = tbase + col; if (arow > SS - 1) arow = SS - 1;
    size_t hoff = ((size_t)b * SS + arow) * 64;
    bf16x8 AH0 = *(const bf16x8*)(hH + hoff + q * 8);
    bf16x8 AH1 = *(const bf16x8*)(hH + hoff + 32 + q * 8);
    bf16x8 AL0 = *(const bf16x8*)(hL + hoff + q * 8);
    bf16x8 AL1 = *(const bf16x8*)(hL + hoff + 32 + q * 8);

    f32x4 acc[4];
#pragma unroll
    for (int nf = 0; nf < 4; ++nf) acc[nf] = (f32x4){0.f, 0.f, 0.f, 0.f};
#pragma unroll
    for (int nf = 0; nf < 4; ++nf) {
      acc[nf] = __builtin_amdgcn_mfma_f32_16x16x32_bf16(AH0, BH[nf][0], acc[nf], 0, 0, 0);
      acc[nf] = __builtin_amdgcn_mfma_f32_16x16x32_bf16(AL0, BH[nf][0], acc[nf], 0, 0, 0);
      acc[nf] = __builtin_amdgcn_mfma_f32_16x16x32_bf16(AH0, BL[nf][0], acc[nf], 0, 0, 0);
      acc[nf] = __builtin_amdgcn_mfma_f32_16x16x32_bf16(AH1, BH[nf][1], acc[nf], 0, 0, 0);
      acc[nf] = __builtin_amdgcn_mfma_f32_16x16x32_bf16(AL1, BH[nf][1], acc[nf], 0, 0, 0);
      acc[nf] = __builtin_amdgcn_mfma_f32_16x16x32_bf16(AH1, BL[nf][1], acc[nf], 0, 0, 0);
    }

    // exp + per-token partial Z over this wave's 64 neurons
    float e0[4], e1[4], e2[4], e3[4];
    float zp[4];
#pragma unroll
    for (int j = 0; j < 4; ++j) {
      e0[j] = __expf(acc[0][j]);
      e1[j] = __expf(acc[1][j]);
      e2[j] = __expf(acc[2][j]);
      e3[j] = __expf(acc[3][j]);
      zp[j] = e0[j] + e1[j] + e2[j] + e3[j];
    }
#pragma unroll
    for (int off = 1; off <= 8; off <<= 1) {
#pragma unroll
      for (int j = 0; j < 4; ++j) zp[j] += __shfl_xor(zp[j], off, 64);
    }
    // exchange across waves (token t16 = q*4 + j handled by this lane-group)
    float zw = (col == 0) ? zp[0] : (col == 1) ? zp[1] : (col == 2) ? zp[2] : zp[3];
    if (col < 4) zred[par][w][q * 4 + col] = zw;
    __syncthreads();
    float r0, r1, r2, r3;
    {
#pragma unroll
      for (int j = 0; j < 4; ++j) {
        int t16 = q * 4 + j;
        float Z = 0.f;
#pragma unroll
        for (int ww = 0; ww < 8; ++ww) Z += zred[par][ww][t16];
        int s = tbase + t16;
        float iv = (s < slim) ? imp[(size_t)b * SS + s] : 0.f;
        float r = iv / Z;
        if (j == 0) r0 = r; else if (j == 1) r1 = r; else if (j == 2) r2 = r; else r3 = r;
      }
    }
    wsum[0] += e0[0] * r0 + e0[1] * r1 + e0[2] * r2 + e0[3] * r3;
    wsum[1] += e1[0] * r0 + e1[1] * r1 + e1[2] * r2 + e1[3] * r3;
    wsum[2] += e2[0] * r0 + e2[1] * r1 + e2[2] * r2 + e2[3] * r3;
    wsum[3] += e3[0] * r0 + e3[1] * r1 + e3[2] * r2 + e3[3] * r3;
    par ^= 1;
  }

  // sum over the 4 lane-groups (tokens) -> every lane holds the full token-sum
#pragma unroll
  for (int nf = 0; nf < 4; ++nf) {
    wsum[nf] += __shfl_xor(wsum[nf], 16, 64);
    wsum[nf] += __shfl_xor(wsum[nf], 32, 64);
  }
  if (q == 0) {
    size_t base = ((size_t)(g * BB + b) * NBB + nb) * 512 + w * 64;
#pragma unroll
    for (int nf = 0; nf < 4; ++nf) partials[base + nf * 16 + col] = wsum[nf];
  }
}

// ---------------- kernel 3: reduce partials + top-k + renormalize ----------------
__global__ __launch_bounds__(512) void k_topk(const float* __restrict__ partials,
                                              float* __restrict__ out) {
  int g = blockIdx.x >> 2;   // 0..2
  int b = blockIdx.x & 3;
  int tid = threadIdx.x;     // neuron 0..511
  int wave = tid >> 6, lane = tid & 63;

  __shared__ float lv[8][8];
  __shared__ int li[8][8];

  float dense = 0.f;
  const float* p = partials + (size_t)(g * BB + b) * NBB * 512 + tid;
  for (int nb = 0; nb < NBB; ++nb) dense += p[nb * 512];

  int K = (g == 0) ? 8 : (g == 1) ? 4 : 6;
  float val = dense;
  float ssum = 0.f;
  int sel = 0;
  for (int it = 0; it < K; ++it) {
    float v = val;
    int idx = tid;
#pragma unroll
    for (int off = 32; off; off >>= 1) {
      float ov = __shfl_xor(v, off, 64);
      int oi = __shfl_xor(idx, off, 64);
      if (ov > v || (ov == v && oi < idx)) { v = ov; idx = oi; }
    }
    if (lane == 0) { lv[wave][0] = v; li[wave][0] = idx; }
    __syncthreads();
    float mv = lv[0][0];
    int mi = li[0][0];
#pragma unroll
    for (int ww = 1; ww < 8; ++ww) {
      float wv2 = lv[ww][0];
      int wi = li[ww][0];
      if (wv2 > mv || (wv2 == mv && wi < mi)) { mv = wv2; mi = wi; }
    }
    ssum += mv;
    if (tid == mi) { sel = 1; val = -3.0e38f; }
    __syncthreads();
  }
  float o = sel ? dense / (ssum + 1e-8f) : 0.f;
  int row = (g == 0) ? 0 : (g == 1) ? 1 : 3;
  out[((size_t)row * BB + b) * 512 + tid] = o;
  if (g == 1) out[((size_t)2 * BB + b) * 512 + tid] = o;
}

extern "C" void kernel_launch(void* const* d_in, const int* in_sizes, int n_in,
                              void* d_out, int out_size, void* d_ws, size_t ws_size,
                              hipStream_t stream) {
  const float* x    = (const float*)d_in[0];
  const float* imp  = (const float*)d_in[1];
  const float* W    = (const float*)d_in[2];
  const float* bias = (const float*)d_in[3];
  const float* emb  = (const float*)d_in[4];
  float* out = (float*)d_out;

  char* ws = (char*)d_ws;
  short* imgH     = (short*)(ws + 0);          // 262144 B
  short* imgL     = (short*)(ws + 262144);     // 262144 B
  short* eH       = (short*)(ws + 524288);     // 196608 B
  short* eL       = (short*)(ws + 720896);     // 196608 B
  short* hH       = (short*)(ws + 917504);     // 2097152 B
  short* hL       = (short*)(ws + 3014656);    // 2097152 B
  float* partials = (float*)(ws + 5111808);    // 12*42*512*4 = 1032192 B

  hipLaunchKernelGGL(k_prep_emb, dim3(384), dim3(256), 0, stream, emb, eH, eL);
  hipLaunchKernelGGL(k_prepw, dim3(32), dim3(256), 0, stream, W, imgH, imgL);
  hipLaunchKernelGGL(k_proj, dim3(512), dim3(128), 0, stream,
                     x, (const float*)imgH, (const float*)imgL, bias, hH, hL);
  hipLaunchKernelGGL(k_pref, dim3(3 * BB * NBB), dim3(512), 0, stream,
                     hH, hL, eH, eL, imp, partials);
  hipLaunchKernelGGL(k_topk, dim3(12), dim3(512), 0, stream, partials, out);
}

// Round 5
// 167.502 us; speedup vs baseline: 2.2943x; 1.0266x over previous
//
#include <hip/hip_runtime.h>

#define NTOT 1536
#define DD 2048
#define BB 4
#define SS 4096
#define NBB 42          // partial blocks per (group,b)
#define TPB 98          // ceil(4096/42)
#define NTILE 7         // 7*16 = 112 >= 98 token slots per block

typedef __attribute__((ext_vector_type(8))) short bf16x8;
typedef __attribute__((ext_vector_type(4))) float f32x4;

__device__ __forceinline__ void split1(float v, unsigned short& hi, unsigned short& lo) {
  unsigned u = __float_as_uint(v);
  hi = (unsigned short)(u >> 16);
  float hf = __uint_as_float(u & 0xffff0000u);
  float r = v - hf;
  lo = (unsigned short)(__float_as_uint(r) >> 16);
}

// ---------------- kernel 0: normalize neuron_emb rows -> hi/lo bf16 ----------------
__global__ __launch_bounds__(256) void k_prep_emb(const float* __restrict__ emb,
                                                  short* __restrict__ eH,
                                                  short* __restrict__ eL) {
  int wave = threadIdx.x >> 6;
  int lane = threadIdx.x & 63;
  int n = blockIdx.x * 4 + wave;          // grid 384 * 4 = 1536 exactly
  float v = emb[n * 64 + lane];
  float ss = v * v;
#pragma unroll
  for (int off = 32; off; off >>= 1) ss += __shfl_xor(ss, off, 64);
  float nrm = fmaxf(sqrtf(ss), 1e-12f);
  float nv = v / nrm;
  unsigned short hi, lo;
  split1(nv, hi, lo);
  eH[n * 64 + lane] = (short)hi;
  eL[n * 64 + lane] = (short)lo;
}

// ---------------- kernel 0b: W -> hi/lo bf16 images, k-tiled + swizzled ----
__global__ __launch_bounds__(256) void k_prepw(const float* __restrict__ W,
                                               short* __restrict__ imgH,
                                               short* __restrict__ imgL) {
  int kt = blockIdx.x;
  for (int idx = threadIdx.x; idx < 4096; idx += 256) {
    int n = idx & 63;
    int q = idx >> 6;          // 0..63
    int p = q >> 3;            // phys slot
    int e = q & 7;
    int s = p ^ (n & 7);       // logical slot
    int k = kt * 64 + s * 8 + e;
    float v = W[k * 64 + n];
    unsigned short hi, lo;
    split1(v, hi, lo);
    int flat = kt * 4096 + n * 64 + p * 8 + e;
    imgH[flat] = (short)hi;
    imgL[flat] = (short)lo;
  }
}

// ---------------- kernel 1: h = x @ W + b via hi/lo bf16 MFMA -> hi/lo h ----------
__device__ __forceinline__ void split8(float4 a, float4 b, bf16x8& hi, bf16x8& lo) {
  float v[8] = {a.x, a.y, a.z, a.w, b.x, b.y, b.z, b.w};
#pragma unroll
  for (int i = 0; i < 8; ++i) {
    unsigned u = __float_as_uint(v[i]);
    hi[i] = (short)(u >> 16);
    float hf = __uint_as_float(u & 0xffff0000u);
    float r = v[i] - hf;
    lo[i] = (short)(__float_as_uint(r) >> 16);
  }
}

__global__ __launch_bounds__(128, 3) void k_proj(const float* __restrict__ x,
                                                 const float* __restrict__ imgHf,
                                                 const float* __restrict__ imgLf,
                                                 const float* __restrict__ bias,
                                                 short* __restrict__ hH,
                                                 short* __restrict__ hL) {
  __shared__ float XAs[2][2048];   // [tok 0..31][64 k] fp32, swizzled slots
  __shared__ short BHs[2][4096];   // bf16 hi image tile (pre-swizzled)
  __shared__ short BLs[2][4096];

  int tid = threadIdx.x;
  int w = tid >> 6;
  int l = tid & 63;
  size_t t0 = (size_t)blockIdx.x * 32;

  int stok = tid >> 4;       // 0..7
  int sslot = tid & 15;      // logical slot (f4 of k)

  float4 xr[4], bhr[4], blr[4];
  f32x4 acc[4];
#pragma unroll
  for (int i = 0; i < 4; ++i) acc[i] = (f32x4){0.f, 0.f, 0.f, 0.f};

  const float4* imgH4 = (const float4*)imgHf;
  const float4* imgL4 = (const float4*)imgLf;

#define LOADT(KT)                                                                  \
  {                                                                                \
    _Pragma("unroll") for (int c = 0; c < 4; ++c) {                                \
      int tok = c * 8 + stok;                                                      \
      xr[c] = *(const float4*)(x + (t0 + tok) * DD + (KT) * 64 + sslot * 4);       \
      bhr[c] = imgH4[(KT) * 512 + c * 128 + tid];                                  \
      blr[c] = imgL4[(KT) * 512 + c * 128 + tid];                                  \
    }                                                                              \
  }

#define WRITET(DB)                                                                 \
  {                                                                                \
    _Pragma("unroll") for (int c = 0; c < 4; ++c) {                                \
      int tok = c * 8 + stok;                                                      \
      *(float4*)(&XAs[DB][tok * 64 + ((sslot ^ (tok & 7)) << 2)]) = xr[c];         \
      *(float4*)(&BHs[DB][c * 1024 + tid * 8]) = bhr[c];                           \
      *(float4*)(&BLs[DB][c * 1024 + tid * 8]) = blr[c];                           \
    }                                                                              \
  }

  LOADT(0);
  WRITET(0);
  __syncthreads();

  int db = 0;
  for (int kt = 0; kt < 32; ++kt) {
    if (kt < 31) LOADT(kt + 1);

    int row = w * 16 + (l & 15);       // block-local token row for A-frag
#pragma unroll
    for (int ks = 0; ks < 2; ++ks) {
      int s0 = ks * 8 + (l >> 4) * 2;
      float4 xa = *(const float4*)(&XAs[db][row * 64 + ((s0 ^ (row & 7)) << 2)]);
      float4 xb = *(const float4*)(&XAs[db][row * 64 + (((s0 + 1) ^ (row & 7)) << 2)]);
      bf16x8 ahi, alo;
      split8(xa, xb, ahi, alo);
#pragma unroll
      for (int nf = 0; nf < 4; ++nf) {
        int n = nf * 16 + (l & 15);
        int p = (ks * 4 + (l >> 4)) ^ (n & 7);
        bf16x8 bh = *(const bf16x8*)(&BHs[db][n * 64 + p * 8]);
        bf16x8 bl = *(const bf16x8*)(&BLs[db][n * 64 + p * 8]);
        acc[nf] = __builtin_amdgcn_mfma_f32_16x16x32_bf16(ahi, bh, acc[nf], 0, 0, 0);
        acc[nf] = __builtin_amdgcn_mfma_f32_16x16x32_bf16(alo, bh, acc[nf], 0, 0, 0);
        acc[nf] = __builtin_amdgcn_mfma_f32_16x16x32_bf16(ahi, bl, acc[nf], 0, 0, 0);
      }
    }

    if (kt < 31) WRITET(db ^ 1);
    __syncthreads();
    db ^= 1;
  }

  // epilogue: token=(l>>4)*4+j (wave-local), n = nf*16 + (l&15); emit hi/lo bf16
#pragma unroll
  for (int nf = 0; nf < 4; ++nf) {
    int n = nf * 16 + (l & 15);
    float bv = bias[n];
#pragma unroll
    for (int j = 0; j < 4; ++j) {
      size_t tok = t0 + w * 16 + (l >> 4) * 4 + j;
      float v = acc[nf][j] + bv;
      unsigned short hi, lo;
      split1(v, hi, lo);
      hH[tok * 64 + n] = (short)hi;
      hL[tok * 64 + n] = (short)lo;
    }
  }
#undef LOADT
#undef WRITET
}

// ---------------- kernel 2: MFMA logits -> softmax -> importance pooling ----------
// Block: 512 thr (8 waves) = one group of 512 neurons; wave owns 64 neurons.
// B-hi fragments (32 VGPR) + nf=3 B-lo (8 VGPR) in registers; B-lo for nf=0..2
// staged in LDS (lane-private slots, conflict-free) to keep demand < 128 VGPR.
__global__ __launch_bounds__(512, 2) void k_pref(const short* __restrict__ hH,
                                                 const short* __restrict__ hL,
                                                 const short* __restrict__ eH,
                                                 const short* __restrict__ eL,
                                                 const float* __restrict__ imp,
                                                 float* __restrict__ partials) {
  int bid = blockIdx.x;
  int g = bid / (BB * NBB);
  int rem = bid % (BB * NBB);
  int b = rem / NBB;
  int nb = rem % NBB;
  int tid = threadIdx.x;
  int w = tid >> 6;
  int l = tid & 63;
  int col = l & 15;
  int q = l >> 4;

  __shared__ short BLs[8 * 3 * 2 * 512];   // 49152 B: [w][nf 0..2][ks][lane*8]
  __shared__ float zred[2][8][16];

  // B-fragments: neuron n = g*512 + w*64 + nf*16 + col; k = ks*32 + q*8 + e
  bf16x8 BH[4][2], BL3[2];
  {
    const short* eHg = eH + ((size_t)(g * 512 + w * 64 + col)) * 64 + q * 8;
    const short* eLg = eL + ((size_t)(g * 512 + w * 64 + col)) * 64 + q * 8;
#pragma unroll
    for (int nf = 0; nf < 4; ++nf) {
#pragma unroll
      for (int ks = 0; ks < 2; ++ks) {
        BH[nf][ks] = *(const bf16x8*)(eHg + nf * 1024 + ks * 32);
        bf16x8 blv = *(const bf16x8*)(eLg + nf * 1024 + ks * 32);
        if (nf < 3) {
          *(bf16x8*)(&BLs[((w * 3 + nf) * 2 + ks) * 512 + l * 8]) = blv;
        } else {
          BL3[ks] = blv;
        }
      }
    }
  }
  __syncthreads();

  int s0 = nb * TPB;
  int slim = s0 + TPB; if (slim > SS) slim = SS;
  float wsum[4] = {0.f, 0.f, 0.f, 0.f};
  int par = 0;

  for (int tile = 0; tile < NTILE; ++tile) {
    int tbase = s0 + tile * 16;
    int arow = tbase + col; if (arow > SS - 1) arow = SS - 1;
    size_t hoff = ((size_t)b * SS + arow) * 64;
    bf16x8 AH0 = *(const bf16x8*)(hH + hoff + q * 8);
    bf16x8 AH1 = *(const bf16x8*)(hH + hoff + 32 + q * 8);
    bf16x8 AL0 = *(const bf16x8*)(hL + hoff + q * 8);
    bf16x8 AL1 = *(const bf16x8*)(hL + hoff + 32 + q * 8);

    f32x4 acc[4];
#pragma unroll
    for (int nf = 0; nf < 4; ++nf) acc[nf] = (f32x4){0.f, 0.f, 0.f, 0.f};
#pragma unroll
    for (int nf = 0; nf < 4; ++nf) {
      bf16x8 bl0, bl1;
      if (nf < 3) {
        bl0 = *(const bf16x8*)(&BLs[((w * 3 + nf) * 2 + 0) * 512 + l * 8]);
        bl1 = *(const bf16x8*)(&BLs[((w * 3 + nf) * 2 + 1) * 512 + l * 8]);
      } else {
        bl0 = BL3[0];
        bl1 = BL3[1];
      }
      acc[nf] = __builtin_amdgcn_mfma_f32_16x16x32_bf16(AH0, BH[nf][0], acc[nf], 0, 0, 0);
      acc[nf] = __builtin_amdgcn_mfma_f32_16x16x32_bf16(AL0, BH[nf][0], acc[nf], 0, 0, 0);
      acc[nf] = __builtin_amdgcn_mfma_f32_16x16x32_bf16(AH0, bl0, acc[nf], 0, 0, 0);
      acc[nf] = __builtin_amdgcn_mfma_f32_16x16x32_bf16(AH1, BH[nf][1], acc[nf], 0, 0, 0);
      acc[nf] = __builtin_amdgcn_mfma_f32_16x16x32_bf16(AL1, BH[nf][1], acc[nf], 0, 0, 0);
      acc[nf] = __builtin_amdgcn_mfma_f32_16x16x32_bf16(AH1, bl1, acc[nf], 0, 0, 0);
    }

    // exp + per-token partial Z over this wave's 64 neurons
    float e0[4], e1[4], e2[4], e3[4];
    float zp[4];
#pragma unroll
    for (int j = 0; j < 4; ++j) {
      e0[j] = __expf(acc[0][j]);
      e1[j] = __expf(acc[1][j]);
      e2[j] = __expf(acc[2][j]);
      e3[j] = __expf(acc[3][j]);
      zp[j] = e0[j] + e1[j] + e2[j] + e3[j];
    }
#pragma unroll
    for (int off = 1; off <= 8; off <<= 1) {
#pragma unroll
      for (int j = 0; j < 4; ++j) zp[j] += __shfl_xor(zp[j], off, 64);
    }
    // exchange across waves (token t16 = q*4 + j handled by this lane-group)
    float zw = (col == 0) ? zp[0] : (col == 1) ? zp[1] : (col == 2) ? zp[2] : zp[3];
    if (col < 4) zred[par][w][q * 4 + col] = zw;
    __syncthreads();
    float r0, r1, r2, r3;
    {
#pragma unroll
      for (int j = 0; j < 4; ++j) {
        int t16 = q * 4 + j;
        float Z = 0.f;
#pragma unroll
        for (int ww = 0; ww < 8; ++ww) Z += zred[par][ww][t16];
        int s = tbase + t16;
        float iv = (s < slim) ? imp[(size_t)b * SS + s] : 0.f;
        float r = iv / Z;
        if (j == 0) r0 = r; else if (j == 1) r1 = r; else if (j == 2) r2 = r; else r3 = r;
      }
    }
    wsum[0] += e0[0] * r0 + e0[1] * r1 + e0[2] * r2 + e0[3] * r3;
    wsum[1] += e1[0] * r0 + e1[1] * r1 + e1[2] * r2 + e1[3] * r3;
    wsum[2] += e2[0] * r0 + e2[1] * r1 + e2[2] * r2 + e2[3] * r3;
    wsum[3] += e3[0] * r0 + e3[1] * r1 + e3[2] * r2 + e3[3] * r3;
    par ^= 1;
  }

  // sum over the 4 lane-groups (tokens) -> every lane holds the full token-sum
#pragma unroll
  for (int nf = 0; nf < 4; ++nf) {
    wsum[nf] += __shfl_xor(wsum[nf], 16, 64);
    wsum[nf] += __shfl_xor(wsum[nf], 32, 64);
  }
  if (q == 0) {
    size_t base = ((size_t)(g * BB + b) * NBB + nb) * 512 + w * 64;
#pragma unroll
    for (int nf = 0; nf < 4; ++nf) partials[base + nf * 16 + col] = wsum[nf];
  }
}

// ---------------- kernel 3: reduce partials + top-k + renormalize ----------------
__global__ __launch_bounds__(512) void k_topk(const float* __restrict__ partials,
                                              float* __restrict__ out) {
  int g = blockIdx.x >> 2;   // 0..2
  int b = blockIdx.x & 3;
  int tid = threadIdx.x;     // neuron 0..511
  int wave = tid >> 6, lane = tid & 63;

  __shared__ float lv[8][8];
  __shared__ int li[8][8];

  float dense = 0.f;
  const float* p = partials + (size_t)(g * BB + b) * NBB * 512 + tid;
  for (int nb = 0; nb < NBB; ++nb) dense += p[nb * 512];

  int K = (g == 0) ? 8 : (g == 1) ? 4 : 6;
  float val = dense;
  float ssum = 0.f;
  int sel = 0;
  for (int it = 0; it < K; ++it) {
    float v = val;
    int idx = tid;
#pragma unroll
    for (int off = 32; off; off >>= 1) {
      float ov = __shfl_xor(v, off, 64);
      int oi = __shfl_xor(idx, off, 64);
      if (ov > v || (ov == v && oi < idx)) { v = ov; idx = oi; }
    }
    if (lane == 0) { lv[wave][0] = v; li[wave][0] = idx; }
    __syncthreads();
    float mv = lv[0][0];
    int mi = li[0][0];
#pragma unroll
    for (int ww = 1; ww < 8; ++ww) {
      float wv2 = lv[ww][0];
      int wi = li[ww][0];
      if (wv2 > mv || (wv2 == mv && wi < mi)) { mv = wv2; mi = wi; }
    }
    ssum += mv;
    if (tid == mi) { sel = 1; val = -3.0e38f; }
    __syncthreads();
  }
  float o = sel ? dense / (ssum + 1e-8f) : 0.f;
  int row = (g == 0) ? 0 : (g == 1) ? 1 : 3;
  out[((size_t)row * BB + b) * 512 + tid] = o;
  if (g == 1) out[((size_t)2 * BB + b) * 512 + tid] = o;
}

extern "C" void kernel_launch(void* const* d_in, const int* in_sizes, int n_in,
                              void* d_out, int out_size, void* d_ws, size_t ws_size,
                              hipStream_t stream) {
  const float* x    = (const float*)d_in[0];
  const float* imp  = (const float*)d_in[1];
  const float* W    = (const float*)d_in[2];
  const float* bias = (const float*)d_in[3];
  const float* emb  = (const float*)d_in[4];
  float* out = (float*)d_out;

  char* ws = (char*)d_ws;
  short* imgH     = (short*)(ws + 0);          // 262144 B
  short* imgL     = (short*)(ws + 262144);     // 262144 B
  short* eH       = (short*)(ws + 524288);     // 196608 B
  short* eL       = (short*)(ws + 720896);     // 196608 B
  short* hH       = (short*)(ws + 917504);     // 2097152 B
  short* hL       = (short*)(ws + 3014656);    // 2097152 B
  float* partials = (float*)(ws + 5111808);    // 12*42*512*4 = 1032192 B

  hipLaunchKernelGGL(k_prep_emb, dim3(384), dim3(256), 0, stream, emb, eH, eL);
  hipLaunchKernelGGL(k_prepw, dim3(32), dim3(256), 0, stream, W, imgH, imgL);
  hipLaunchKernelGGL(k_proj, dim3(512), dim3(128), 0, stream,
                     x, (const float*)imgH, (const float*)imgL, bias, hH, hL);
  hipLaunchKernelGGL(k_pref, dim3(3 * BB * NBB), dim3(512), 0, stream,
                     hH, hL, eH, eL, imp, partials);
  hipLaunchKernelGGL(k_topk, dim3(12), dim3(512), 0, stream, partials, out);
}

// Round 6
// 164.675 us; speedup vs baseline: 2.3337x; 1.0172x over previous
//
#include <hip/hip_runtime.h>

#define NTOT 1536
#define DD 2048
#define BB 4
#define SS 4096
#define NBB 42          // partial blocks per (group,b)
#define TPB 98          // ceil(4096/42)
#define NTILE 7         // 7*16 = 112 >= 98 token slots per block

typedef __attribute__((ext_vector_type(8))) short bf16x8;
typedef __attribute__((ext_vector_type(4))) float f32x4;

__device__ __forceinline__ void split1(float v, unsigned short& hi, unsigned short& lo) {
  unsigned u = __float_as_uint(v);
  hi = (unsigned short)(u >> 16);
  float hf = __uint_as_float(u & 0xffff0000u);
  float r = v - hf;
  lo = (unsigned short)(__float_as_uint(r) >> 16);
}

// ---------------- kernel 0: normalize neuron_emb rows -> hi/lo bf16 ----------------
__global__ __launch_bounds__(256) void k_prep_emb(const float* __restrict__ emb,
                                                  short* __restrict__ eH,
                                                  short* __restrict__ eL) {
  int wave = threadIdx.x >> 6;
  int lane = threadIdx.x & 63;
  int n = blockIdx.x * 4 + wave;          // grid 384 * 4 = 1536 exactly
  float v = emb[n * 64 + lane];
  float ss = v * v;
#pragma unroll
  for (int off = 32; off; off >>= 1) ss += __shfl_xor(ss, off, 64);
  float nrm = fmaxf(sqrtf(ss), 1e-12f);
  float nv = v / nrm;
  unsigned short hi, lo;
  split1(nv, hi, lo);
  eH[n * 64 + lane] = (short)hi;
  eL[n * 64 + lane] = (short)lo;
}

// ---------------- kernel 0b: W -> hi/lo bf16 images, k-tiled + swizzled ----
__global__ __launch_bounds__(256) void k_prepw(const float* __restrict__ W,
                                               short* __restrict__ imgH,
                                               short* __restrict__ imgL) {
  int kt = blockIdx.x;
  for (int idx = threadIdx.x; idx < 4096; idx += 256) {
    int n = idx & 63;
    int q = idx >> 6;          // 0..63
    int p = q >> 3;            // phys slot
    int e = q & 7;
    int s = p ^ (n & 7);       // logical slot
    int k = kt * 64 + s * 8 + e;
    float v = W[k * 64 + n];
    unsigned short hi, lo;
    split1(v, hi, lo);
    int flat = kt * 4096 + n * 64 + p * 8 + e;
    imgH[flat] = (short)hi;
    imgL[flat] = (short)lo;
  }
}

// ---------------- kernel 1: h = x @ W + b via hi/lo bf16 MFMA -> hi/lo h ----------
__device__ __forceinline__ void split8(float4 a, float4 b, bf16x8& hi, bf16x8& lo) {
  float v[8] = {a.x, a.y, a.z, a.w, b.x, b.y, b.z, b.w};
#pragma unroll
  for (int i = 0; i < 8; ++i) {
    unsigned u = __float_as_uint(v[i]);
    hi[i] = (short)(u >> 16);
    float hf = __uint_as_float(u & 0xffff0000u);
    float r = v[i] - hf;
    lo[i] = (short)(__float_as_uint(r) >> 16);
  }
}

__global__ __launch_bounds__(128, 3) void k_proj(const float* __restrict__ x,
                                                 const float* __restrict__ imgHf,
                                                 const float* __restrict__ imgLf,
                                                 const float* __restrict__ bias,
                                                 short* __restrict__ hH,
                                                 short* __restrict__ hL) {
  __shared__ float XAs[2][2048];   // [tok 0..31][64 k] fp32, swizzled slots
  __shared__ short BHs[2][4096];   // bf16 hi image tile (pre-swizzled)
  __shared__ short BLs[2][4096];

  int tid = threadIdx.x;
  int w = tid >> 6;
  int l = tid & 63;
  size_t t0 = (size_t)blockIdx.x * 32;

  int stok = tid >> 4;       // 0..7
  int sslot = tid & 15;      // logical slot (f4 of k)

  float4 xr[4], bhr[4], blr[4];
  f32x4 acc[4];
#pragma unroll
  for (int i = 0; i < 4; ++i) acc[i] = (f32x4){0.f, 0.f, 0.f, 0.f};

  const float4* imgH4 = (const float4*)imgHf;
  const float4* imgL4 = (const float4*)imgLf;

#define LOADT(KT)                                                                  \
  {                                                                                \
    _Pragma("unroll") for (int c = 0; c < 4; ++c) {                                \
      int tok = c * 8 + stok;                                                      \
      xr[c] = *(const float4*)(x + (t0 + tok) * DD + (KT) * 64 + sslot * 4);       \
      bhr[c] = imgH4[(KT) * 512 + c * 128 + tid];                                  \
      blr[c] = imgL4[(KT) * 512 + c * 128 + tid];                                  \
    }                                                                              \
  }

#define WRITET(DB)                                                                 \
  {                                                                                \
    _Pragma("unroll") for (int c = 0; c < 4; ++c) {                                \
      int tok = c * 8 + stok;                                                      \
      *(float4*)(&XAs[DB][tok * 64 + ((sslot ^ (tok & 7)) << 2)]) = xr[c];         \
      *(float4*)(&BHs[DB][c * 1024 + tid * 8]) = bhr[c];                           \
      *(float4*)(&BLs[DB][c * 1024 + tid * 8]) = blr[c];                           \
    }                                                                              \
  }

  LOADT(0);
  WRITET(0);
  __syncthreads();

  int db = 0;
  for (int kt = 0; kt < 32; ++kt) {
    if (kt < 31) LOADT(kt + 1);

    int row = w * 16 + (l & 15);       // block-local token row for A-frag
#pragma unroll
    for (int ks = 0; ks < 2; ++ks) {
      int s0 = ks * 8 + (l >> 4) * 2;
      float4 xa = *(const float4*)(&XAs[db][row * 64 + ((s0 ^ (row & 7)) << 2)]);
      float4 xb = *(const float4*)(&XAs[db][row * 64 + (((s0 + 1) ^ (row & 7)) << 2)]);
      bf16x8 ahi, alo;
      split8(xa, xb, ahi, alo);
#pragma unroll
      for (int nf = 0; nf < 4; ++nf) {
        int n = nf * 16 + (l & 15);
        int p = (ks * 4 + (l >> 4)) ^ (n & 7);
        bf16x8 bh = *(const bf16x8*)(&BHs[db][n * 64 + p * 8]);
        bf16x8 bl = *(const bf16x8*)(&BLs[db][n * 64 + p * 8]);
        acc[nf] = __builtin_amdgcn_mfma_f32_16x16x32_bf16(ahi, bh, acc[nf], 0, 0, 0);
        acc[nf] = __builtin_amdgcn_mfma_f32_16x16x32_bf16(alo, bh, acc[nf], 0, 0, 0);
        acc[nf] = __builtin_amdgcn_mfma_f32_16x16x32_bf16(ahi, bl, acc[nf], 0, 0, 0);
      }
    }

    if (kt < 31) WRITET(db ^ 1);
    __syncthreads();
    db ^= 1;
  }

  // epilogue: token=(l>>4)*4+j (wave-local), n = nf*16 + (l&15); emit hi/lo bf16
#pragma unroll
  for (int nf = 0; nf < 4; ++nf) {
    int n = nf * 16 + (l & 15);
    float bv = bias[n];
#pragma unroll
    for (int j = 0; j < 4; ++j) {
      size_t tok = t0 + w * 16 + (l >> 4) * 4 + j;
      float v = acc[nf][j] + bv;
      unsigned short hi, lo;
      split1(v, hi, lo);
      hH[tok * 64 + n] = (short)hi;
      hL[tok * 64 + n] = (short)lo;
    }
  }
#undef LOADT
#undef WRITET
}

// ---------------- kernel 2: MFMA logits -> softmax -> importance pooling ----------
// Block: 512 thr (8 waves) = one group of 512 neurons; wave owns 64 neurons.
// Register diet: B-hi fragments (32 VGPR) in registers; ALL B-lo fragments in
// LDS (lane-private 16B slots, conflict-free); no e[] arrays — exp recomputed
// after Z is known. Target live state ~100 VGPR < 128 cap -> no scratch.
__global__ __launch_bounds__(512, 2) void k_pref(const short* __restrict__ hH,
                                                 const short* __restrict__ hL,
                                                 const short* __restrict__ eH,
                                                 const short* __restrict__ eL,
                                                 const float* __restrict__ imp,
                                                 float* __restrict__ partials) {
  int bid = blockIdx.x;
  int g = bid / (BB * NBB);
  int rem = bid % (BB * NBB);
  int b = rem / NBB;
  int nb = rem % NBB;
  int tid = threadIdx.x;
  int w = tid >> 6;
  int l = tid & 63;
  int col = l & 15;
  int q = l >> 4;

  __shared__ short BLs[4 * 2 * 512 * 8];   // 65536 B: [nf][ks][tid] 16B slots
  __shared__ float zred[2][8][16];

  // B-fragments: neuron n = g*512 + w*64 + nf*16 + col; k = ks*32 + q*8 + e
  bf16x8 BH[4][2];
  {
    const short* eHg = eH + ((size_t)(g * 512 + w * 64 + col)) * 64 + q * 8;
    const short* eLg = eL + ((size_t)(g * 512 + w * 64 + col)) * 64 + q * 8;
#pragma unroll
    for (int nf = 0; nf < 4; ++nf) {
#pragma unroll
      for (int ks = 0; ks < 2; ++ks) {
        BH[nf][ks] = *(const bf16x8*)(eHg + nf * 1024 + ks * 32);
        bf16x8 blv = *(const bf16x8*)(eLg + nf * 1024 + ks * 32);
        *(bf16x8*)(&BLs[((nf * 2 + ks) * 512 + tid) * 8]) = blv;
      }
    }
  }
  __syncthreads();

  int s0 = nb * TPB;
  int slim = s0 + TPB; if (slim > SS) slim = SS;
  float wsum[4] = {0.f, 0.f, 0.f, 0.f};
  int par = 0;

  for (int tile = 0; tile < NTILE; ++tile) {
    int tbase = s0 + tile * 16;
    int arow = tbase + col; if (arow > SS - 1) arow = SS - 1;
    size_t hoff = ((size_t)b * SS + arow) * 64;
    bf16x8 AH0 = *(const bf16x8*)(hH + hoff + q * 8);
    bf16x8 AH1 = *(const bf16x8*)(hH + hoff + 32 + q * 8);
    bf16x8 AL0 = *(const bf16x8*)(hL + hoff + q * 8);
    bf16x8 AL1 = *(const bf16x8*)(hL + hoff + 32 + q * 8);

    f32x4 acc[4];
#pragma unroll
    for (int nf = 0; nf < 4; ++nf) acc[nf] = (f32x4){0.f, 0.f, 0.f, 0.f};
#pragma unroll
    for (int nf = 0; nf < 4; ++nf) {
      bf16x8 bl0 = *(const bf16x8*)(&BLs[((nf * 2 + 0) * 512 + tid) * 8]);
      bf16x8 bl1 = *(const bf16x8*)(&BLs[((nf * 2 + 1) * 512 + tid) * 8]);
      acc[nf] = __builtin_amdgcn_mfma_f32_16x16x32_bf16(AH0, BH[nf][0], acc[nf], 0, 0, 0);
      acc[nf] = __builtin_amdgcn_mfma_f32_16x16x32_bf16(AL0, BH[nf][0], acc[nf], 0, 0, 0);
      acc[nf] = __builtin_amdgcn_mfma_f32_16x16x32_bf16(AH0, bl0, acc[nf], 0, 0, 0);
      acc[nf] = __builtin_amdgcn_mfma_f32_16x16x32_bf16(AH1, BH[nf][1], acc[nf], 0, 0, 0);
      acc[nf] = __builtin_amdgcn_mfma_f32_16x16x32_bf16(AL1, BH[nf][1], acc[nf], 0, 0, 0);
      acc[nf] = __builtin_amdgcn_mfma_f32_16x16x32_bf16(AH1, bl1, acc[nf], 0, 0, 0);
    }

    // per-token partial Z over this wave's 64 neurons (exp recomputed later)
    float zp[4];
#pragma unroll
    for (int j = 0; j < 4; ++j) {
      zp[j] = __expf(acc[0][j]) + __expf(acc[1][j]) +
              __expf(acc[2][j]) + __expf(acc[3][j]);
    }
#pragma unroll
    for (int off = 1; off <= 8; off <<= 1) {
#pragma unroll
      for (int j = 0; j < 4; ++j) zp[j] += __shfl_xor(zp[j], off, 64);
    }
    // exchange across waves (token t16 = q*4 + j handled by this lane-group)
    float zw = (col == 0) ? zp[0] : (col == 1) ? zp[1] : (col == 2) ? zp[2] : zp[3];
    if (col < 4) zred[par][w][q * 4 + col] = zw;
    __syncthreads();
    float r0, r1, r2, r3;
    {
#pragma unroll
      for (int j = 0; j < 4; ++j) {
        int t16 = q * 4 + j;
        float Z = 0.f;
#pragma unroll
        for (int ww = 0; ww < 8; ++ww) Z += zred[par][ww][t16];
        int s = tbase + t16;
        float iv = (s < slim) ? imp[(size_t)b * SS + s] : 0.f;
        float r = iv / Z;
        if (j == 0) r0 = r; else if (j == 1) r1 = r; else if (j == 2) r2 = r; else r3 = r;
      }
    }
#pragma unroll
    for (int nf = 0; nf < 4; ++nf) {
      wsum[nf] += __expf(acc[nf][0]) * r0 + __expf(acc[nf][1]) * r1 +
                  __expf(acc[nf][2]) * r2 + __expf(acc[nf][3]) * r3;
    }
    par ^= 1;
  }

  // sum over the 4 lane-groups (tokens) -> every lane holds the full token-sum
#pragma unroll
  for (int nf = 0; nf < 4; ++nf) {
    wsum[nf] += __shfl_xor(wsum[nf], 16, 64);
    wsum[nf] += __shfl_xor(wsum[nf], 32, 64);
  }
  if (q == 0) {
    size_t base = ((size_t)(g * BB + b) * NBB + nb) * 512 + w * 64;
#pragma unroll
    for (int nf = 0; nf < 4; ++nf) partials[base + nf * 16 + col] = wsum[nf];
  }
}

// ---------------- kernel 3: reduce partials + top-k + renormalize ----------------
__global__ __launch_bounds__(512) void k_topk(const float* __restrict__ partials,
                                              float* __restrict__ out) {
  int g = blockIdx.x >> 2;   // 0..2
  int b = blockIdx.x & 3;
  int tid = threadIdx.x;     // neuron 0..511
  int wave = tid >> 6, lane = tid & 63;

  __shared__ float lv[8][8];
  __shared__ int li[8][8];

  float dense = 0.f;
  const float* p = partials + (size_t)(g * BB + b) * NBB * 512 + tid;
  for (int nb = 0; nb < NBB; ++nb) dense += p[nb * 512];

  int K = (g == 0) ? 8 : (g == 1) ? 4 : 6;
  float val = dense;
  float ssum = 0.f;
  int sel = 0;
  for (int it = 0; it < K; ++it) {
    float v = val;
    int idx = tid;
#pragma unroll
    for (int off = 32; off; off >>= 1) {
      float ov = __shfl_xor(v, off, 64);
      int oi = __shfl_xor(idx, off, 64);
      if (ov > v || (ov == v && oi < idx)) { v = ov; idx = oi; }
    }
    if (lane == 0) { lv[wave][0] = v; li[wave][0] = idx; }
    __syncthreads();
    float mv = lv[0][0];
    int mi = li[0][0];
#pragma unroll
    for (int ww = 1; ww < 8; ++ww) {
      float wv2 = lv[ww][0];
      int wi = li[ww][0];
      if (wv2 > mv || (wv2 == mv && wi < mi)) { mv = wv2; mi = wi; }
    }
    ssum += mv;
    if (tid == mi) { sel = 1; val = -3.0e38f; }
    __syncthreads();
  }
  float o = sel ? dense / (ssum + 1e-8f) : 0.f;
  int row = (g == 0) ? 0 : (g == 1) ? 1 : 3;
  out[((size_t)row * BB + b) * 512 + tid] = o;
  if (g == 1) out[((size_t)2 * BB + b) * 512 + tid] = o;
}

extern "C" void kernel_launch(void* const* d_in, const int* in_sizes, int n_in,
                              void* d_out, int out_size, void* d_ws, size_t ws_size,
                              hipStream_t stream) {
  const float* x    = (const float*)d_in[0];
  const float* imp  = (const float*)d_in[1];
  const float* W    = (const float*)d_in[2];
  const float* bias = (const float*)d_in[3];
  const float* emb  = (const float*)d_in[4];
  float* out = (float*)d_out;

  char* ws = (char*)d_ws;
  short* imgH     = (short*)(ws + 0);          // 262144 B
  short* imgL     = (short*)(ws + 262144);     // 262144 B
  short* eH       = (short*)(ws + 524288);     // 196608 B
  short* eL       = (short*)(ws + 720896);     // 196608 B
  short* hH       = (short*)(ws + 917504);     // 2097152 B
  short* hL       = (short*)(ws + 3014656);    // 2097152 B
  float* partials = (float*)(ws + 5111808);    // 12*42*512*4 = 1032192 B

  hipLaunchKernelGGL(k_prep_emb, dim3(384), dim3(256), 0, stream, emb, eH, eL);
  hipLaunchKernelGGL(k_prepw, dim3(32), dim3(256), 0, stream, W, imgH, imgL);
  hipLaunchKernelGGL(k_proj, dim3(512), dim3(128), 0, stream,
                     x, (const float*)imgH, (const float*)imgL, bias, hH, hL);
  hipLaunchKernelGGL(k_pref, dim3(3 * BB * NBB), dim3(512), 0, stream,
                     hH, hL, eH, eL, imp, partials);
  hipLaunchKernelGGL(k_topk, dim3(12), dim3(512), 0, stream, partials, out);
}

// Round 7
// 95.532 us; speedup vs baseline: 4.0228x; 1.7238x over previous
//
#include <hip/hip_runtime.h>

#define NTOT 1536
#define DD 2048
#define BB 4
#define SS 4096
#define NBB 42          // partial blocks per (group,b)
#define TPB 98          // ceil(4096/42)
#define NTILE 7         // 7*16 = 112 >= 98 token slots per block

typedef __attribute__((ext_vector_type(8))) short bf16x8;
typedef __attribute__((ext_vector_type(4))) float f32x4;

__device__ __forceinline__ void split1(float v, unsigned short& hi, unsigned short& lo) {
  unsigned u = __float_as_uint(v);
  hi = (unsigned short)(u >> 16);
  float hf = __uint_as_float(u & 0xffff0000u);
  float r = v - hf;
  lo = (unsigned short)(__float_as_uint(r) >> 16);
}

// ---------------- kernel 0: normalize neuron_emb rows -> hi/lo bf16 ----------------
__global__ __launch_bounds__(256) void k_prep_emb(const float* __restrict__ emb,
                                                  short* __restrict__ eH,
                                                  short* __restrict__ eL) {
  int wave = threadIdx.x >> 6;
  int lane = threadIdx.x & 63;
  int n = blockIdx.x * 4 + wave;          // grid 384 * 4 = 1536 exactly
  float v = emb[n * 64 + lane];
  float ss = v * v;
#pragma unroll
  for (int off = 32; off; off >>= 1) ss += __shfl_xor(ss, off, 64);
  float nrm = fmaxf(sqrtf(ss), 1e-12f);
  float nv = v / nrm;
  unsigned short hi, lo;
  split1(nv, hi, lo);
  eH[n * 64 + lane] = (short)hi;
  eL[n * 64 + lane] = (short)lo;
}

// ---------------- kernel 0b: W -> hi/lo bf16 images, k-tiled + swizzled ----
__global__ __launch_bounds__(256) void k_prepw(const float* __restrict__ W,
                                               short* __restrict__ imgH,
                                               short* __restrict__ imgL) {
  int kt = blockIdx.x;
  for (int idx = threadIdx.x; idx < 4096; idx += 256) {
    int n = idx & 63;
    int q = idx >> 6;          // 0..63
    int p = q >> 3;            // phys slot
    int e = q & 7;
    int s = p ^ (n & 7);       // logical slot
    int k = kt * 64 + s * 8 + e;
    float v = W[k * 64 + n];
    unsigned short hi, lo;
    split1(v, hi, lo);
    int flat = kt * 4096 + n * 64 + p * 8 + e;
    imgH[flat] = (short)hi;
    imgL[flat] = (short)lo;
  }
}

// ---------------- kernel 1: h = x @ W + b via hi/lo bf16 MFMA -> hi/lo h ----------
__device__ __forceinline__ void split8(float4 a, float4 b, bf16x8& hi, bf16x8& lo) {
  float v[8] = {a.x, a.y, a.z, a.w, b.x, b.y, b.z, b.w};
#pragma unroll
  for (int i = 0; i < 8; ++i) {
    unsigned u = __float_as_uint(v[i]);
    hi[i] = (short)(u >> 16);
    float hf = __uint_as_float(u & 0xffff0000u);
    float r = v[i] - hf;
    lo[i] = (short)(__float_as_uint(r) >> 16);
  }
}

__global__ __launch_bounds__(128, 3) void k_proj(const float* __restrict__ x,
                                                 const float* __restrict__ imgHf,
                                                 const float* __restrict__ imgLf,
                                                 const float* __restrict__ bias,
                                                 short* __restrict__ hH,
                                                 short* __restrict__ hL) {
  __shared__ float XAs[2][2048];   // [tok 0..31][64 k] fp32, swizzled slots
  __shared__ short BHs[2][4096];   // bf16 hi image tile (pre-swizzled)
  __shared__ short BLs[2][4096];

  int tid = threadIdx.x;
  int w = tid >> 6;
  int l = tid & 63;
  size_t t0 = (size_t)blockIdx.x * 32;

  int stok = tid >> 4;       // 0..7
  int sslot = tid & 15;      // logical slot (f4 of k)

  float4 xr[4], bhr[4], blr[4];
  f32x4 acc[4];
#pragma unroll
  for (int i = 0; i < 4; ++i) acc[i] = (f32x4){0.f, 0.f, 0.f, 0.f};

  const float4* imgH4 = (const float4*)imgHf;
  const float4* imgL4 = (const float4*)imgLf;

#define LOADT(KT)                                                                  \
  {                                                                                \
    _Pragma("unroll") for (int c = 0; c < 4; ++c) {                                \
      int tok = c * 8 + stok;                                                      \
      xr[c] = *(const float4*)(x + (t0 + tok) * DD + (KT) * 64 + sslot * 4);       \
      bhr[c] = imgH4[(KT) * 512 + c * 128 + tid];                                  \
      blr[c] = imgL4[(KT) * 512 + c * 128 + tid];                                  \
    }                                                                              \
  }

#define WRITET(DB)                                                                 \
  {                                                                                \
    _Pragma("unroll") for (int c = 0; c < 4; ++c) {                                \
      int tok = c * 8 + stok;                                                      \
      *(float4*)(&XAs[DB][tok * 64 + ((sslot ^ (tok & 7)) << 2)]) = xr[c];         \
      *(float4*)(&BHs[DB][c * 1024 + tid * 8]) = bhr[c];                           \
      *(float4*)(&BLs[DB][c * 1024 + tid * 8]) = blr[c];                           \
    }                                                                              \
  }

  LOADT(0);
  WRITET(0);
  __syncthreads();

  int db = 0;
  for (int kt = 0; kt < 32; ++kt) {
    if (kt < 31) LOADT(kt + 1);

    int row = w * 16 + (l & 15);       // block-local token row for A-frag
#pragma unroll
    for (int ks = 0; ks < 2; ++ks) {
      int s0 = ks * 8 + (l >> 4) * 2;
      float4 xa = *(const float4*)(&XAs[db][row * 64 + ((s0 ^ (row & 7)) << 2)]);
      float4 xb = *(const float4*)(&XAs[db][row * 64 + (((s0 + 1) ^ (row & 7)) << 2)]);
      bf16x8 ahi, alo;
      split8(xa, xb, ahi, alo);
#pragma unroll
      for (int nf = 0; nf < 4; ++nf) {
        int n = nf * 16 + (l & 15);
        int p = (ks * 4 + (l >> 4)) ^ (n & 7);
        bf16x8 bh = *(const bf16x8*)(&BHs[db][n * 64 + p * 8]);
        bf16x8 bl = *(const bf16x8*)(&BLs[db][n * 64 + p * 8]);
        acc[nf] = __builtin_amdgcn_mfma_f32_16x16x32_bf16(ahi, bh, acc[nf], 0, 0, 0);
        acc[nf] = __builtin_amdgcn_mfma_f32_16x16x32_bf16(alo, bh, acc[nf], 0, 0, 0);
        acc[nf] = __builtin_amdgcn_mfma_f32_16x16x32_bf16(ahi, bl, acc[nf], 0, 0, 0);
      }
    }

    if (kt < 31) WRITET(db ^ 1);
    __syncthreads();
    db ^= 1;
  }

  // epilogue: token=(l>>4)*4+j (wave-local), n = nf*16 + (l&15); emit hi/lo bf16
#pragma unroll
  for (int nf = 0; nf < 4; ++nf) {
    int n = nf * 16 + (l & 15);
    float bv = bias[n];
#pragma unroll
    for (int j = 0; j < 4; ++j) {
      size_t tok = t0 + w * 16 + (l >> 4) * 4 + j;
      float v = acc[nf][j] + bv;
      unsigned short hi, lo;
      split1(v, hi, lo);
      hH[tok * 64 + n] = (short)hi;
      hL[tok * 64 + n] = (short)lo;
    }
  }
#undef LOADT
#undef WRITET
}

// ---------------- kernel 2: MFMA logits -> softmax -> importance pooling ----------
// Block: 512 thr (8 waves) = one group of 512 neurons; wave owns 64 neurons.
// B-hi fragments (32 VGPR) in registers; ALL B-lo fragments in LDS (lane-private
// 16B slots, conflict-free); exp recomputed after Z. The tile loop is
// `#pragma unroll 1`: full unroll (NTILE=7 constexpr) was hoisting 7 tiles of
// A-loads (~112 VGPR) -> demand ~200 -> 20 dwords/thread/tile scratch spill
// (observed as 143-163 MB WRITE_SIZE in rounds 4-6).
__global__ __launch_bounds__(512, 2) void k_pref(const short* __restrict__ hH,
                                                 const short* __restrict__ hL,
                                                 const short* __restrict__ eH,
                                                 const short* __restrict__ eL,
                                                 const float* __restrict__ imp,
                                                 float* __restrict__ partials) {
  int bid = blockIdx.x;
  int g = bid / (BB * NBB);
  int rem = bid % (BB * NBB);
  int b = rem / NBB;
  int nb = rem % NBB;
  int tid = threadIdx.x;
  int w = tid >> 6;
  int l = tid & 63;
  int col = l & 15;
  int q = l >> 4;

  __shared__ short BLs[4 * 2 * 512 * 8];   // 65536 B: [nf][ks][tid] 16B slots
  __shared__ float zred[2][8][16];

  // B-fragments: neuron n = g*512 + w*64 + nf*16 + col; k = ks*32 + q*8 + e
  bf16x8 BH[4][2];
  {
    const short* eHg = eH + ((size_t)(g * 512 + w * 64 + col)) * 64 + q * 8;
    const short* eLg = eL + ((size_t)(g * 512 + w * 64 + col)) * 64 + q * 8;
#pragma unroll
    for (int nf = 0; nf < 4; ++nf) {
#pragma unroll
      for (int ks = 0; ks < 2; ++ks) {
        BH[nf][ks] = *(const bf16x8*)(eHg + nf * 1024 + ks * 32);
        bf16x8 blv = *(const bf16x8*)(eLg + nf * 1024 + ks * 32);
        *(bf16x8*)(&BLs[((nf * 2 + ks) * 512 + tid) * 8]) = blv;
      }
    }
  }
  __syncthreads();

  int s0 = nb * TPB;
  int slim = s0 + TPB; if (slim > SS) slim = SS;
  float wsum[4] = {0.f, 0.f, 0.f, 0.f};
  int par = 0;

#pragma unroll 1
  for (int tile = 0; tile < NTILE; ++tile) {
    int tbase = s0 + tile * 16;
    int arow = tbase + col; if (arow > SS - 1) arow = SS - 1;
    size_t hoff = ((size_t)b * SS + arow) * 64;
    bf16x8 AH0 = *(const bf16x8*)(hH + hoff + q * 8);
    bf16x8 AH1 = *(const bf16x8*)(hH + hoff + 32 + q * 8);
    bf16x8 AL0 = *(const bf16x8*)(hL + hoff + q * 8);
    bf16x8 AL1 = *(const bf16x8*)(hL + hoff + 32 + q * 8);

    f32x4 acc[4];
#pragma unroll
    for (int nf = 0; nf < 4; ++nf) acc[nf] = (f32x4){0.f, 0.f, 0.f, 0.f};
#pragma unroll
    for (int nf = 0; nf < 4; ++nf) {
      bf16x8 bl0 = *(const bf16x8*)(&BLs[((nf * 2 + 0) * 512 + tid) * 8]);
      bf16x8 bl1 = *(const bf16x8*)(&BLs[((nf * 2 + 1) * 512 + tid) * 8]);
      acc[nf] = __builtin_amdgcn_mfma_f32_16x16x32_bf16(AH0, BH[nf][0], acc[nf], 0, 0, 0);
      acc[nf] = __builtin_amdgcn_mfma_f32_16x16x32_bf16(AL0, BH[nf][0], acc[nf], 0, 0, 0);
      acc[nf] = __builtin_amdgcn_mfma_f32_16x16x32_bf16(AH0, bl0, acc[nf], 0, 0, 0);
      acc[nf] = __builtin_amdgcn_mfma_f32_16x16x32_bf16(AH1, BH[nf][1], acc[nf], 0, 0, 0);
      acc[nf] = __builtin_amdgcn_mfma_f32_16x16x32_bf16(AL1, BH[nf][1], acc[nf], 0, 0, 0);
      acc[nf] = __builtin_amdgcn_mfma_f32_16x16x32_bf16(AH1, bl1, acc[nf], 0, 0, 0);
    }

    // per-token partial Z over this wave's 64 neurons (exp recomputed later)
    float zp[4];
#pragma unroll
    for (int j = 0; j < 4; ++j) {
      zp[j] = __expf(acc[0][j]) + __expf(acc[1][j]) +
              __expf(acc[2][j]) + __expf(acc[3][j]);
    }
#pragma unroll
    for (int off = 1; off <= 8; off <<= 1) {
#pragma unroll
      for (int j = 0; j < 4; ++j) zp[j] += __shfl_xor(zp[j], off, 64);
    }
    // exchange across waves (token t16 = q*4 + j handled by this lane-group)
    float zw = (col == 0) ? zp[0] : (col == 1) ? zp[1] : (col == 2) ? zp[2] : zp[3];
    if (col < 4) zred[par][w][q * 4 + col] = zw;
    __syncthreads();
    float r0, r1, r2, r3;
    {
#pragma unroll
      for (int j = 0; j < 4; ++j) {
        int t16 = q * 4 + j;
        float Z = 0.f;
#pragma unroll
        for (int ww = 0; ww < 8; ++ww) Z += zred[par][ww][t16];
        int s = tbase + t16;
        float iv = (s < slim) ? imp[(size_t)b * SS + s] : 0.f;
        float r = iv / Z;
        if (j == 0) r0 = r; else if (j == 1) r1 = r; else if (j == 2) r2 = r; else r3 = r;
      }
    }
#pragma unroll
    for (int nf = 0; nf < 4; ++nf) {
      wsum[nf] += __expf(acc[nf][0]) * r0 + __expf(acc[nf][1]) * r1 +
                  __expf(acc[nf][2]) * r2 + __expf(acc[nf][3]) * r3;
    }
    par ^= 1;
  }

  // sum over the 4 lane-groups (tokens) -> every lane holds the full token-sum
#pragma unroll
  for (int nf = 0; nf < 4; ++nf) {
    wsum[nf] += __shfl_xor(wsum[nf], 16, 64);
    wsum[nf] += __shfl_xor(wsum[nf], 32, 64);
  }
  if (q == 0) {
    size_t base = ((size_t)(g * BB + b) * NBB + nb) * 512 + w * 64;
#pragma unroll
    for (int nf = 0; nf < 4; ++nf) partials[base + nf * 16 + col] = wsum[nf];
  }
}

// ---------------- kernel 3: reduce partials + top-k + renormalize ----------------
__global__ __launch_bounds__(512) void k_topk(const float* __restrict__ partials,
                                              float* __restrict__ out) {
  int g = blockIdx.x >> 2;   // 0..2
  int b = blockIdx.x & 3;
  int tid = threadIdx.x;     // neuron 0..511
  int wave = tid >> 6, lane = tid & 63;

  __shared__ float lv[8][8];
  __shared__ int li[8][8];

  float dense = 0.f;
  const float* p = partials + (size_t)(g * BB + b) * NBB * 512 + tid;
  for (int nb = 0; nb < NBB; ++nb) dense += p[nb * 512];

  int K = (g == 0) ? 8 : (g == 1) ? 4 : 6;
  float val = dense;
  float ssum = 0.f;
  int sel = 0;
  for (int it = 0; it < K; ++it) {
    float v = val;
    int idx = tid;
#pragma unroll
    for (int off = 32; off; off >>= 1) {
      float ov = __shfl_xor(v, off, 64);
      int oi = __shfl_xor(idx, off, 64);
      if (ov > v || (ov == v && oi < idx)) { v = ov; idx = oi; }
    }
    if (lane == 0) { lv[wave][0] = v; li[wave][0] = idx; }
    __syncthreads();
    float mv = lv[0][0];
    int mi = li[0][0];
#pragma unroll
    for (int ww = 1; ww < 8; ++ww) {
      float wv2 = lv[ww][0];
      int wi = li[ww][0];
      if (wv2 > mv || (wv2 == mv && wi < mi)) { mv = wv2; mi = wi; }
    }
    ssum += mv;
    if (tid == mi) { sel = 1; val = -3.0e38f; }
    __syncthreads();
  }
  float o = sel ? dense / (ssum + 1e-8f) : 0.f;
  int row = (g == 0) ? 0 : (g == 1) ? 1 : 3;
  out[((size_t)row * BB + b) * 512 + tid] = o;
  if (g == 1) out[((size_t)2 * BB + b) * 512 + tid] = o;
}

extern "C" void kernel_launch(void* const* d_in, const int* in_sizes, int n_in,
                              void* d_out, int out_size, void* d_ws, size_t ws_size,
                              hipStream_t stream) {
  const float* x    = (const float*)d_in[0];
  const float* imp  = (const float*)d_in[1];
  const float* W    = (const float*)d_in[2];
  const float* bias = (const float*)d_in[3];
  const float* emb  = (const float*)d_in[4];
  float* out = (float*)d_out;

  char* ws = (char*)d_ws;
  short* imgH     = (short*)(ws + 0);          // 262144 B
  short* imgL     = (short*)(ws + 262144);     // 262144 B
  short* eH       = (short*)(ws + 524288);     // 196608 B
  short* eL       = (short*)(ws + 720896);     // 196608 B
  short* hH       = (short*)(ws + 917504);     // 2097152 B
  short* hL       = (short*)(ws + 3014656);    // 2097152 B
  float* partials = (float*)(ws + 5111808);    // 12*42*512*4 = 1032192 B

  hipLaunchKernelGGL(k_prep_emb, dim3(384), dim3(256), 0, stream, emb, eH, eL);
  hipLaunchKernelGGL(k_prepw, dim3(32), dim3(256), 0, stream, W, imgH, imgL);
  hipLaunchKernelGGL(k_proj, dim3(512), dim3(128), 0, stream,
                     x, (const float*)imgH, (const float*)imgL, bias, hH, hL);
  hipLaunchKernelGGL(k_pref, dim3(3 * BB * NBB), dim3(512), 0, stream,
                     hH, hL, eH, eL, imp, partials);
  hipLaunchKernelGGL(k_topk, dim3(12), dim3(512), 0, stream, partials, out);
}

// Round 8
// 90.297 us; speedup vs baseline: 4.2560x; 1.0580x over previous
//
#include <hip/hip_runtime.h>

#define NTOT 1536
#define DD 2048
#define BB 4
#define SS 4096
#define NBB 42          // partial blocks per (group,b)
#define TPB 98          // ceil(4096/42)
#define NTILE 7         // 7*16 = 112 >= 98 token slots per block

typedef __attribute__((ext_vector_type(8))) short bf16x8;
typedef __attribute__((ext_vector_type(4))) float f32x4;

__device__ __forceinline__ void split1(float v, unsigned short& hi, unsigned short& lo) {
  unsigned u = __float_as_uint(v);
  hi = (unsigned short)(u >> 16);
  float hf = __uint_as_float(u & 0xffff0000u);
  float r = v - hf;
  lo = (unsigned short)(__float_as_uint(r) >> 16);
}

// ---------------- kernel 0: merged prep (emb normalize + W images) -------------
// blocks 0..383: normalize neuron_emb rows -> hi/lo bf16
// blocks 384..415: W -> hi/lo bf16 images, k-tiled + swizzled
__global__ __launch_bounds__(256) void k_prep(const float* __restrict__ emb,
                                              const float* __restrict__ W,
                                              short* __restrict__ eH,
                                              short* __restrict__ eL,
                                              short* __restrict__ imgH,
                                              short* __restrict__ imgL) {
  int bid = blockIdx.x;
  if (bid < 384) {
    int wave = threadIdx.x >> 6;
    int lane = threadIdx.x & 63;
    int n = bid * 4 + wave;               // 384*4 = 1536 exactly
    float v = emb[n * 64 + lane];
    float ss = v * v;
#pragma unroll
    for (int off = 32; off; off >>= 1) ss += __shfl_xor(ss, off, 64);
    float nrm = fmaxf(sqrtf(ss), 1e-12f);
    float nv = v / nrm;
    unsigned short hi, lo;
    split1(nv, hi, lo);
    eH[n * 64 + lane] = (short)hi;
    eL[n * 64 + lane] = (short)lo;
  } else {
    int kt = bid - 384;                   // 0..31
    for (int idx = threadIdx.x; idx < 4096; idx += 256) {
      int n = idx & 63;
      int q = idx >> 6;          // 0..63
      int p = q >> 3;            // phys slot
      int e = q & 7;
      int s = p ^ (n & 7);       // logical slot
      int k = kt * 64 + s * 8 + e;
      float v = W[k * 64 + n];
      unsigned short hi, lo;
      split1(v, hi, lo);
      int flat = kt * 4096 + n * 64 + p * 8 + e;
      imgH[flat] = (short)hi;
      imgL[flat] = (short)lo;
    }
  }
}

// ---------------- kernel 1: h = x @ W + b via hi/lo bf16 MFMA -> hi/lo h ----------
// 256 thr (4 waves), tile 32 tok x 64 n, K-tile 64. Wave w: tokens (w&1)*16..+15,
// n-half (w>>1)*32. 8 waves/CU at 2 blocks/CU (was 4 waves/CU with 128 thr).
__global__ __launch_bounds__(256, 2) void k_proj(const float* __restrict__ x,
                                                 const float* __restrict__ imgHf,
                                                 const float* __restrict__ imgLf,
                                                 const float* __restrict__ bias,
                                                 short* __restrict__ hH,
                                                 short* __restrict__ hL) {
  __shared__ float XAs[2][2048];   // [tok 0..31][64 k] fp32, swizzled slots
  __shared__ short BHs[2][4096];   // bf16 hi image tile (pre-swizzled)
  __shared__ short BLs[2][4096];

  int tid = threadIdx.x;           // 0..255
  int w = tid >> 6;                // 0..3
  int l = tid & 63;
  size_t t0 = (size_t)blockIdx.x * 32;

  int ty = tid >> 4;               // staging row 0..15
  int sslot = tid & 15;            // logical slot (f4 of k)

  int th = (w & 1) * 16;           // token half
  int nh = (w >> 1) * 32;          // n half

  float4 xr[2], bhr[2], blr[2];
  f32x4 acc[2];
#pragma unroll
  for (int i = 0; i < 2; ++i) acc[i] = (f32x4){0.f, 0.f, 0.f, 0.f};

  const float4* imgH4 = (const float4*)imgHf;
  const float4* imgL4 = (const float4*)imgLf;

#define LOADT(KT)                                                                  \
  {                                                                                \
    _Pragma("unroll") for (int c = 0; c < 2; ++c) {                                \
      int tok = c * 16 + ty;                                                       \
      xr[c] = *(const float4*)(x + (t0 + tok) * DD + (KT) * 64 + sslot * 4);       \
      bhr[c] = imgH4[(KT) * 512 + c * 256 + tid];                                  \
      blr[c] = imgL4[(KT) * 512 + c * 256 + tid];                                  \
    }                                                                              \
  }

#define WRITET(DB)                                                                 \
  {                                                                                \
    _Pragma("unroll") for (int c = 0; c < 2; ++c) {                                \
      int tok = c * 16 + ty;                                                       \
      *(float4*)(&XAs[DB][tok * 64 + ((sslot ^ (tok & 7)) << 2)]) = xr[c];         \
      *(float4*)(&BHs[DB][(c * 256 + tid) * 8]) = bhr[c];                          \
      *(float4*)(&BLs[DB][(c * 256 + tid) * 8]) = blr[c];                          \
    }                                                                              \
  }

  LOADT(0);
  WRITET(0);
  __syncthreads();

  int db = 0;
  for (int kt = 0; kt < 32; ++kt) {
    if (kt < 31) LOADT(kt + 1);

    int row = th + (l & 15);       // block-local token row for A-frag
#pragma unroll
    for (int ks = 0; ks < 2; ++ks) {
      int s0 = ks * 8 + (l >> 4) * 2;
      float4 xa = *(const float4*)(&XAs[db][row * 64 + ((s0 ^ (row & 7)) << 2)]);
      float4 xb = *(const float4*)(&XAs[db][row * 64 + (((s0 + 1) ^ (row & 7)) << 2)]);
      bf16x8 ahi, alo;
      {
        float v[8] = {xa.x, xa.y, xa.z, xa.w, xb.x, xb.y, xb.z, xb.w};
#pragma unroll
        for (int i = 0; i < 8; ++i) {
          unsigned u = __float_as_uint(v[i]);
          ahi[i] = (short)(u >> 16);
          float hf = __uint_as_float(u & 0xffff0000u);
          float r = v[i] - hf;
          alo[i] = (short)(__float_as_uint(r) >> 16);
        }
      }
#pragma unroll
      for (int nf = 0; nf < 2; ++nf) {
        int n = nh + nf * 16 + (l & 15);
        int p = (ks * 4 + (l >> 4)) ^ (n & 7);
        bf16x8 bh = *(const bf16x8*)(&BHs[db][n * 64 + p * 8]);
        bf16x8 bl = *(const bf16x8*)(&BLs[db][n * 64 + p * 8]);
        acc[nf] = __builtin_amdgcn_mfma_f32_16x16x32_bf16(ahi, bh, acc[nf], 0, 0, 0);
        acc[nf] = __builtin_amdgcn_mfma_f32_16x16x32_bf16(alo, bh, acc[nf], 0, 0, 0);
        acc[nf] = __builtin_amdgcn_mfma_f32_16x16x32_bf16(ahi, bl, acc[nf], 0, 0, 0);
      }
    }

    if (kt < 31) WRITET(db ^ 1);
    __syncthreads();
    db ^= 1;
  }

  // epilogue: token = t0 + th + (l>>4)*4+j, n = nh + nf*16 + (l&15)
#pragma unroll
  for (int nf = 0; nf < 2; ++nf) {
    int n = nh + nf * 16 + (l & 15);
    float bv = bias[n];
#pragma unroll
    for (int j = 0; j < 4; ++j) {
      size_t tok = t0 + th + (l >> 4) * 4 + j;
      float v = acc[nf][j] + bv;
      unsigned short hi, lo;
      split1(v, hi, lo);
      hH[tok * 64 + n] = (short)hi;
      hL[tok * 64 + n] = (short)lo;
    }
  }
#undef LOADT
#undef WRITET
}

// ---------------- kernel 2: MFMA logits -> softmax -> importance pooling ----------
// Block: 512 thr (8 waves) = one group of 512 neurons; wave owns 64 neurons.
// B-hi in registers (32 VGPR), B-lo in LDS (lane-private, conflict-free), exp
// recomputed after Z. Tile loop `#pragma unroll 1` (full unroll caused 143+ MB
// scratch spill, rounds 4-6). A-fragments software-pipelined one tile ahead
// (+16 VGPR, demand ~112 < 128 cliff).
__global__ __launch_bounds__(512, 2) void k_pref(const short* __restrict__ hH,
                                                 const short* __restrict__ hL,
                                                 const short* __restrict__ eH,
                                                 const short* __restrict__ eL,
                                                 const float* __restrict__ imp,
                                                 float* __restrict__ partials) {
  int bid = blockIdx.x;
  int g = bid / (BB * NBB);
  int rem = bid % (BB * NBB);
  int b = rem / NBB;
  int nb = rem % NBB;
  int tid = threadIdx.x;
  int w = tid >> 6;
  int l = tid & 63;
  int col = l & 15;
  int q = l >> 4;

  __shared__ short BLs[4 * 2 * 512 * 8];   // 65536 B: [nf][ks][tid] 16B slots
  __shared__ float zred[2][8][16];

  // B-fragments: neuron n = g*512 + w*64 + nf*16 + col; k = ks*32 + q*8 + e
  bf16x8 BH[4][2];
  {
    const short* eHg = eH + ((size_t)(g * 512 + w * 64 + col)) * 64 + q * 8;
    const short* eLg = eL + ((size_t)(g * 512 + w * 64 + col)) * 64 + q * 8;
#pragma unroll
    for (int nf = 0; nf < 4; ++nf) {
#pragma unroll
      for (int ks = 0; ks < 2; ++ks) {
        BH[nf][ks] = *(const bf16x8*)(eHg + nf * 1024 + ks * 32);
        bf16x8 blv = *(const bf16x8*)(eLg + nf * 1024 + ks * 32);
        *(bf16x8*)(&BLs[((nf * 2 + ks) * 512 + tid) * 8]) = blv;
      }
    }
  }
  __syncthreads();

  int s0 = nb * TPB;
  int slim = s0 + TPB; if (slim > SS) slim = SS;
  float wsum[4] = {0.f, 0.f, 0.f, 0.f};
  int par = 0;

#define LOADA(TB, A0, A1, A2, A3)                                        \
  {                                                                      \
    int arow = (TB) + col; if (arow > SS - 1) arow = SS - 1;             \
    size_t hoff = ((size_t)b * SS + arow) * 64;                          \
    A0 = *(const bf16x8*)(hH + hoff + q * 8);                            \
    A1 = *(const bf16x8*)(hH + hoff + 32 + q * 8);                       \
    A2 = *(const bf16x8*)(hL + hoff + q * 8);                            \
    A3 = *(const bf16x8*)(hL + hoff + 32 + q * 8);                       \
  }

  bf16x8 AH0, AH1, AL0, AL1, nH0, nH1, nL0, nL1;
  LOADA(s0, AH0, AH1, AL0, AL1);

#pragma unroll 1
  for (int tile = 0; tile < NTILE; ++tile) {
    int tbase = s0 + tile * 16;
    if (tile < NTILE - 1) LOADA(tbase + 16, nH0, nH1, nL0, nL1);

    f32x4 acc[4];
#pragma unroll
    for (int nf = 0; nf < 4; ++nf) acc[nf] = (f32x4){0.f, 0.f, 0.f, 0.f};
#pragma unroll
    for (int nf = 0; nf < 4; ++nf) {
      bf16x8 bl0 = *(const bf16x8*)(&BLs[((nf * 2 + 0) * 512 + tid) * 8]);
      bf16x8 bl1 = *(const bf16x8*)(&BLs[((nf * 2 + 1) * 512 + tid) * 8]);
      acc[nf] = __builtin_amdgcn_mfma_f32_16x16x32_bf16(AH0, BH[nf][0], acc[nf], 0, 0, 0);
      acc[nf] = __builtin_amdgcn_mfma_f32_16x16x32_bf16(AL0, BH[nf][0], acc[nf], 0, 0, 0);
      acc[nf] = __builtin_amdgcn_mfma_f32_16x16x32_bf16(AH0, bl0, acc[nf], 0, 0, 0);
      acc[nf] = __builtin_amdgcn_mfma_f32_16x16x32_bf16(AH1, BH[nf][1], acc[nf], 0, 0, 0);
      acc[nf] = __builtin_amdgcn_mfma_f32_16x16x32_bf16(AL1, BH[nf][1], acc[nf], 0, 0, 0);
      acc[nf] = __builtin_amdgcn_mfma_f32_16x16x32_bf16(AH1, bl1, acc[nf], 0, 0, 0);
    }

    // per-token partial Z over this wave's 64 neurons (exp recomputed later)
    float zp[4];
#pragma unroll
    for (int j = 0; j < 4; ++j) {
      zp[j] = __expf(acc[0][j]) + __expf(acc[1][j]) +
              __expf(acc[2][j]) + __expf(acc[3][j]);
    }
#pragma unroll
    for (int off = 1; off <= 8; off <<= 1) {
#pragma unroll
      for (int j = 0; j < 4; ++j) zp[j] += __shfl_xor(zp[j], off, 64);
    }
    // exchange across waves (token t16 = q*4 + j handled by this lane-group)
    float zw = (col == 0) ? zp[0] : (col == 1) ? zp[1] : (col == 2) ? zp[2] : zp[3];
    if (col < 4) zred[par][w][q * 4 + col] = zw;
    __syncthreads();
    float r0, r1, r2, r3;
    {
#pragma unroll
      for (int j = 0; j < 4; ++j) {
        int t16 = q * 4 + j;
        float Z = 0.f;
#pragma unroll
        for (int ww = 0; ww < 8; ++ww) Z += zred[par][ww][t16];
        int s = tbase + t16;
        float iv = (s < slim) ? imp[(size_t)b * SS + s] : 0.f;
        float r = iv / Z;
        if (j == 0) r0 = r; else if (j == 1) r1 = r; else if (j == 2) r2 = r; else r3 = r;
      }
    }
#pragma unroll
    for (int nf = 0; nf < 4; ++nf) {
      wsum[nf] += __expf(acc[nf][0]) * r0 + __expf(acc[nf][1]) * r1 +
                  __expf(acc[nf][2]) * r2 + __expf(acc[nf][3]) * r3;
    }
    AH0 = nH0; AH1 = nH1; AL0 = nL0; AL1 = nL1;
    par ^= 1;
  }
#undef LOADA

  // sum over the 4 lane-groups (tokens) -> every lane holds the full token-sum
#pragma unroll
  for (int nf = 0; nf < 4; ++nf) {
    wsum[nf] += __shfl_xor(wsum[nf], 16, 64);
    wsum[nf] += __shfl_xor(wsum[nf], 32, 64);
  }
  if (q == 0) {
    size_t base = ((size_t)(g * BB + b) * NBB + nb) * 512 + w * 64;
#pragma unroll
    for (int nf = 0; nf < 4; ++nf) partials[base + nf * 16 + col] = wsum[nf];
  }
}

// ---------------- kernel 3: reduce partials + top-k + renormalize ----------------
__global__ __launch_bounds__(512) void k_topk(const float* __restrict__ partials,
                                              float* __restrict__ out) {
  int g = blockIdx.x >> 2;   // 0..2
  int b = blockIdx.x & 3;
  int tid = threadIdx.x;     // neuron 0..511
  int wave = tid >> 6, lane = tid & 63;

  __shared__ float lv[8][8];
  __shared__ int li[8][8];

  float dense = 0.f;
  const float* p = partials + (size_t)(g * BB + b) * NBB * 512 + tid;
  for (int nb = 0; nb < NBB; ++nb) dense += p[nb * 512];

  int K = (g == 0) ? 8 : (g == 1) ? 4 : 6;
  float val = dense;
  float ssum = 0.f;
  int sel = 0;
  for (int it = 0; it < K; ++it) {
    float v = val;
    int idx = tid;
#pragma unroll
    for (int off = 32; off; off >>= 1) {
      float ov = __shfl_xor(v, off, 64);
      int oi = __shfl_xor(idx, off, 64);
      if (ov > v || (ov == v && oi < idx)) { v = ov; idx = oi; }
    }
    if (lane == 0) { lv[wave][0] = v; li[wave][0] = idx; }
    __syncthreads();
    float mv = lv[0][0];
    int mi = li[0][0];
#pragma unroll
    for (int ww = 1; ww < 8; ++ww) {
      float wv2 = lv[ww][0];
      int wi = li[ww][0];
      if (wv2 > mv || (wv2 == mv && wi < mi)) { mv = wv2; mi = wi; }
    }
    ssum += mv;
    if (tid == mi) { sel = 1; val = -3.0e38f; }
    __syncthreads();
  }
  float o = sel ? dense / (ssum + 1e-8f) : 0.f;
  int row = (g == 0) ? 0 : (g == 1) ? 1 : 3;
  out[((size_t)row * BB + b) * 512 + tid] = o;
  if (g == 1) out[((size_t)2 * BB + b) * 512 + tid] = o;
}

extern "C" void kernel_launch(void* const* d_in, const int* in_sizes, int n_in,
                              void* d_out, int out_size, void* d_ws, size_t ws_size,
                              hipStream_t stream) {
  const float* x    = (const float*)d_in[0];
  const float* imp  = (const float*)d_in[1];
  const float* W    = (const float*)d_in[2];
  const float* bias = (const float*)d_in[3];
  const float* emb  = (const float*)d_in[4];
  float* out = (float*)d_out;

  char* ws = (char*)d_ws;
  short* imgH     = (short*)(ws + 0);          // 262144 B
  short* imgL     = (short*)(ws + 262144);     // 262144 B
  short* eH       = (short*)(ws + 524288);     // 196608 B
  short* eL       = (short*)(ws + 720896);     // 196608 B
  short* hH       = (short*)(ws + 917504);     // 2097152 B
  short* hL       = (short*)(ws + 3014656);    // 2097152 B
  float* partials = (float*)(ws + 5111808);    // 12*42*512*4 = 1032192 B

  hipLaunchKernelGGL(k_prep, dim3(416), dim3(256), 0, stream, emb, W, eH, eL, imgH, imgL);
  hipLaunchKernelGGL(k_proj, dim3(512), dim3(256), 0, stream,
                     x, (const float*)imgH, (const float*)imgL, bias, hH, hL);
  hipLaunchKernelGGL(k_pref, dim3(3 * BB * NBB), dim3(512), 0, stream,
                     hH, hL, eH, eL, imp, partials);
  hipLaunchKernelGGL(k_topk, dim3(12), dim3(512), 0, stream, partials, out);
}